// Round 1
// baseline (912.524 us; speedup 1.0000x reference)
//
#include <hip/hip_runtime.h>

#define NN 100000
#define NE 1600000
#define DF 512
#define NIDX 10000

__device__ __forceinline__ float eluf(float x) { return x > 0.f ? x : expm1f(x); }

// ---------------- GEMM: C[M,N] = A[M,K] @ B[K,N], BM=BN=64, BK=32 ----------------
template<bool ELU_A>
__global__ __launch_bounds__(256) void gemm64(const float* __restrict__ A, const float* __restrict__ B,
                                              float* __restrict__ C, int M, int N, int K) {
  __shared__ float As[32][68];
  __shared__ float Bs[32][68];
  const int tid = threadIdx.x;
  const int m0 = blockIdx.x * 64;
  const int n0 = blockIdx.y * 64;
  const int tx = tid & 15, ty = tid >> 4;
  float acc[4][4] = {};
  for (int k0 = 0; k0 < K; k0 += 32) {
    for (int j = tid; j < 512; j += 256) {  // A tile: 64 rows x 32 cols, transposed into As[k][m]
      int r = j >> 3, kq = j & 7;
      int row = m0 + r;
      float4 v = make_float4(0.f, 0.f, 0.f, 0.f);
      if (row < M) v = *(const float4*)&A[(size_t)row * K + k0 + kq * 4];
      if (ELU_A) { v.x = eluf(v.x); v.y = eluf(v.y); v.z = eluf(v.z); v.w = eluf(v.w); }
      As[kq * 4 + 0][r] = v.x; As[kq * 4 + 1][r] = v.y;
      As[kq * 4 + 2][r] = v.z; As[kq * 4 + 3][r] = v.w;
    }
    for (int j = tid; j < 512; j += 256) {  // B tile: 32 rows x 64 cols
      int kr = j >> 4, nq = j & 15;
      *(float4*)&Bs[kr][nq * 4] = *(const float4*)&B[(size_t)(k0 + kr) * N + n0 + nq * 4];
    }
    __syncthreads();
#pragma unroll
    for (int kk = 0; kk < 32; ++kk) {
      float4 a4 = *(const float4*)&As[kk][ty * 4];
      float4 b4 = *(const float4*)&Bs[kk][tx * 4];
      float av[4] = {a4.x, a4.y, a4.z, a4.w};
      float bv[4] = {b4.x, b4.y, b4.z, b4.w};
#pragma unroll
      for (int i = 0; i < 4; ++i)
#pragma unroll
        for (int jj = 0; jj < 4; ++jj)
          acc[i][jj] = fmaf(av[i], bv[jj], acc[i][jj]);
    }
    __syncthreads();
  }
#pragma unroll
  for (int i = 0; i < 4; ++i) {
    int row = m0 + ty * 4 + i;
    if (row < M) {
      float4 v = make_float4(acc[i][0], acc[i][1], acc[i][2], acc[i][3]);
      *(float4*)&C[(size_t)row * N + n0 + tx * 4] = v;
    }
  }
}

// ---------------- per-node attention scores s_src/s_dst ----------------
template<int U>
__global__ __launch_bounds__(256) void s_kernel(const float* __restrict__ h, const float* __restrict__ asrc,
                                                const float* __restrict__ adst, float* __restrict__ s_src,
                                                float* __restrict__ s_dst, int n) {
  int node = blockIdx.x * 256 + threadIdx.x;
  if (node >= n) return;
  const float* hp = h + (size_t)node * 8 * U;
#pragma unroll
  for (int hh = 0; hh < 8; ++hh) {
    float ss = 0.f, dd = 0.f;
#pragma unroll
    for (int u = 0; u < U; u += 4) {
      float4 hv = *(const float4*)&hp[hh * U + u];
      float4 av = *(const float4*)&asrc[hh * U + u];
      float4 bv = *(const float4*)&adst[hh * U + u];
      ss += hv.x * av.x + hv.y * av.y + hv.z * av.z + hv.w * av.w;
      dd += hv.x * bv.x + hv.y * bv.y + hv.z * bv.z + hv.w * bv.w;
    }
    s_src[(size_t)node * 8 + hh] = ss;
    s_dst[(size_t)node * 8 + hh] = dd;
  }
}

// ---------------- CSR build ----------------
__global__ void count_kernel(const int2* __restrict__ edges, int* __restrict__ cnt, int E) {
  int e = blockIdx.x * blockDim.x + threadIdx.x;
  if (e < E) atomicAdd(&cnt[edges[e].x], 1);
}

__global__ __launch_bounds__(1024) void scan_kernel(const int* __restrict__ cnt, int* __restrict__ row_off,
                                                    int* __restrict__ cursor, int n) {
  __shared__ int sums[1024];
  int tid = threadIdx.x;
  int per = (n + 1023) >> 10;
  int start = tid * per;
  int end = start + per; if (end > n) end = n;
  int s = 0;
  for (int i = start; i < end; ++i) s += cnt[i];
  sums[tid] = s;
  __syncthreads();
  for (int off = 1; off < 1024; off <<= 1) {
    int v = (tid >= off) ? sums[tid - off] : 0;
    __syncthreads();
    sums[tid] += v;
    __syncthreads();
  }
  int run = sums[tid] - s;  // exclusive prefix
  for (int i = start; i < end; ++i) {
    row_off[i] = run; cursor[i] = run; run += cnt[i];
  }
  if (tid == 1023) row_off[n] = sums[1023];
}

__global__ void scatter_kernel(const int2* __restrict__ edges, int* __restrict__ cursor,
                               int* __restrict__ sorted_src, int E) {
  int e = blockIdx.x * blockDim.x + threadIdx.x;
  if (e < E) {
    int2 ed = edges[e];
    int pos = atomicAdd(&cursor[ed.x], 1);
    sorted_src[pos] = ed.y;
  }
}

// ---------------- layer-1 aggregation: wave per node, lane = (h*8+u) ----------------
__global__ __launch_bounds__(256) void agg1_kernel(const int* __restrict__ row_off, const int* __restrict__ srcs,
                                                   const float* __restrict__ s_src, const float* __restrict__ s_dst,
                                                   const float* __restrict__ h, float* __restrict__ out, int n) {
  int wave = (blockIdx.x * 256 + threadIdx.x) >> 6;
  int lane = threadIdx.x & 63;
  if (wave >= n) return;
  int hh = lane >> 3;
  float sd = s_dst[(size_t)wave * 8 + hh];
  int beg = row_off[wave], end = row_off[wave + 1];
  float acc = 0.f, den = 0.f;
  for (int i = beg; i < end; ++i) {
    int src = srcs[i];
    float e = sd + s_src[(size_t)src * 8 + hh];
    e = e > 0.f ? e : 0.2f * e;
    float ex = __expf(e);
    den += ex;
    acc = fmaf(ex, h[(size_t)src * 64 + lane], acc);
  }
  out[(size_t)wave * 64 + lane] = acc / fmaxf(den, 1e-9f);
}

// ---------------- layer-2 aggregation + head average: lane = (h*8 + o/2) ----------------
__global__ __launch_bounds__(256) void agg2_kernel(const int* __restrict__ row_off, const int* __restrict__ srcs,
                                                   const float* __restrict__ s_src, const float* __restrict__ s_dst,
                                                   const float* __restrict__ h2, float* __restrict__ out, int n) {
  int wave = (blockIdx.x * 256 + threadIdx.x) >> 6;
  int lane = threadIdx.x & 63;
  if (wave >= n) return;
  int hh = lane >> 3, o2 = lane & 7;
  float sd = s_dst[(size_t)wave * 8 + hh];
  int beg = row_off[wave], end = row_off[wave + 1];
  float a0 = 0.f, a1 = 0.f, den = 0.f;
  for (int i = beg; i < end; ++i) {
    int src = srcs[i];
    float e = sd + s_src[(size_t)src * 8 + hh];
    e = e > 0.f ? e : 0.2f * e;
    float ex = __expf(e);
    den += ex;
    float2 v = *(const float2*)&h2[(size_t)src * 128 + hh * 16 + o2 * 2];
    a0 = fmaf(ex, v.x, a0);
    a1 = fmaf(ex, v.y, a1);
  }
  float r0 = a0 / fmaxf(den, 1e-9f);
  float r1 = a1 / fmaxf(den, 1e-9f);
  // sum over heads: lanes differing in bits 3..5 share the same o2
  for (int m = 8; m < 64; m <<= 1) {
    r0 += __shfl_xor(r0, m, 64);
    r1 += __shfl_xor(r1, m, 64);
  }
  if (lane < 8) {
    float2 w = make_float2(r0 * 0.125f, r1 * 0.125f);
    *(float2*)&out[(size_t)wave * 16 + lane * 2] = w;
  }
}

// ---------------- final index gather ----------------
__global__ void gather_kernel(const float* __restrict__ out2, const int* __restrict__ idx,
                              float* __restrict__ out, int ni) {
  int t = blockIdx.x * blockDim.x + threadIdx.x;
  if (t < ni * 4) {
    int i = t >> 2, q = t & 3;
    int node = idx[i];
    *(float4*)&out[(size_t)i * 16 + q * 4] = *(const float4*)&out2[(size_t)node * 16 + q * 4];
  }
}

extern "C" void kernel_launch(void* const* d_in, const int* in_sizes, int n_in,
                              void* d_out, int out_size, void* d_ws, size_t ws_size,
                              hipStream_t stream) {
  const float* x   = (const float*)d_in[0];
  const int2* edges = (const int2*)d_in[1];
  const int* indices = (const int*)d_in[2];
  const float* W1  = (const float*)d_in[3];
  const float* a1s = (const float*)d_in[4];
  const float* a1d = (const float*)d_in[5];
  const float* W2  = (const float*)d_in[6];
  const float* a2s = (const float*)d_in[7];
  const float* a2d = (const float*)d_in[8];
  float* out = (float*)d_out;

  char* ws = (char*)d_ws;
  size_t off = 0;
  auto alloc = [&](size_t bytes) {
    void* p = ws + off;
    off = (off + bytes + 255) & ~(size_t)255;
    return p;
  };
  float* h1    = (float*)alloc((size_t)NN * 64 * 4);   // reused as out2 later
  float* out2  = h1;
  float* s1src = (float*)alloc((size_t)NN * 8 * 4);    // reused for layer 2
  float* s1dst = (float*)alloc((size_t)NN * 8 * 4);
  float* out1  = (float*)alloc((size_t)NN * 64 * 4);
  float* h2    = (float*)alloc((size_t)NN * 128 * 4);
  int* cnt     = (int*)alloc((size_t)NN * 4);
  int* row_off = (int*)alloc(((size_t)NN + 1) * 4);
  int* cursor  = (int*)alloc((size_t)NN * 4);
  int* ssrc    = (int*)alloc((size_t)NE * 4);

  hipMemsetAsync(cnt, 0, (size_t)NN * 4, stream);

  dim3 b256(256);
  // layer 1 GEMM: h1 = x @ W1  ([100000,512] x [512,64])
  gemm64<false><<<dim3((NN + 63) / 64, 1), b256, 0, stream>>>(x, W1, h1, NN, 64, 512);
  // scores
  s_kernel<8><<<dim3((NN + 255) / 256), b256, 0, stream>>>(h1, a1s, a1d, s1src, s1dst, NN);
  // CSR build (by dst)
  count_kernel<<<dim3((NE + 255) / 256), b256, 0, stream>>>(edges, cnt, NE);
  scan_kernel<<<1, 1024, 0, stream>>>(cnt, row_off, cursor, NN);
  scatter_kernel<<<dim3((NE + 255) / 256), b256, 0, stream>>>(edges, cursor, ssrc, NE);
  // layer 1 aggregation
  agg1_kernel<<<dim3(NN / 4), b256, 0, stream>>>(row_off, ssrc, s1src, s1dst, h1, out1, NN);
  // layer 2 GEMM with fused ELU on input: h2 = elu(out1) @ W2  ([100000,64] x [64,128])
  gemm64<true><<<dim3((NN + 63) / 64, 2), b256, 0, stream>>>(out1, W2, h2, NN, 128, 64);
  // layer 2 scores (reuse s buffers)
  s_kernel<16><<<dim3((NN + 255) / 256), b256, 0, stream>>>(h2, a2s, a2d, s1src, s1dst, NN);
  // layer 2 aggregation + head average
  agg2_kernel<<<dim3(NN / 4), b256, 0, stream>>>(row_off, ssrc, s1src, s1dst, h2, out2, NN);
  // final gather
  gather_kernel<<<dim3((NIDX * 4 + 255) / 256), b256, 0, stream>>>(out2, indices, out, NIDX);
}

// Round 2
// 696.155 us; speedup vs baseline: 1.3108x; 1.3108x over previous
//
#include <hip/hip_runtime.h>

#define NN 100000
#define NE 1600000
#define DF 512
#define NIDX 10000
#define SCAN_NB ((NN + 1023) / 1024)   // 98 blocks, 1024 elements each

__device__ __forceinline__ float eluf(float x) { return x > 0.f ? x : expm1f(x); }

// ---------------- GEMM: C[M,N] = A[M,K] @ B[K,N], BM=BN=64, BK=32 ----------------
template<bool ELU_A>
__global__ __launch_bounds__(256) void gemm64(const float* __restrict__ A, const float* __restrict__ B,
                                              float* __restrict__ C, int M, int N, int K) {
  __shared__ float As[32][68];
  __shared__ float Bs[32][68];
  const int tid = threadIdx.x;
  const int m0 = blockIdx.x * 64;
  const int n0 = blockIdx.y * 64;
  const int tx = tid & 15, ty = tid >> 4;
  float acc[4][4] = {};
  for (int k0 = 0; k0 < K; k0 += 32) {
    for (int j = tid; j < 512; j += 256) {  // A tile: 64 rows x 32 cols, transposed into As[k][m]
      int r = j >> 3, kq = j & 7;
      int row = m0 + r;
      float4 v = make_float4(0.f, 0.f, 0.f, 0.f);
      if (row < M) v = *(const float4*)&A[(size_t)row * K + k0 + kq * 4];
      if (ELU_A) { v.x = eluf(v.x); v.y = eluf(v.y); v.z = eluf(v.z); v.w = eluf(v.w); }
      As[kq * 4 + 0][r] = v.x; As[kq * 4 + 1][r] = v.y;
      As[kq * 4 + 2][r] = v.z; As[kq * 4 + 3][r] = v.w;
    }
    for (int j = tid; j < 512; j += 256) {  // B tile: 32 rows x 64 cols
      int kr = j >> 4, nq = j & 15;
      *(float4*)&Bs[kr][nq * 4] = *(const float4*)&B[(size_t)(k0 + kr) * N + n0 + nq * 4];
    }
    __syncthreads();
#pragma unroll
    for (int kk = 0; kk < 32; ++kk) {
      float4 a4 = *(const float4*)&As[kk][ty * 4];
      float4 b4 = *(const float4*)&Bs[kk][tx * 4];
      float av[4] = {a4.x, a4.y, a4.z, a4.w};
      float bv[4] = {b4.x, b4.y, b4.z, b4.w};
#pragma unroll
      for (int i = 0; i < 4; ++i)
#pragma unroll
        for (int jj = 0; jj < 4; ++jj)
          acc[i][jj] = fmaf(av[i], bv[jj], acc[i][jj]);
    }
    __syncthreads();
  }
#pragma unroll
  for (int i = 0; i < 4; ++i) {
    int row = m0 + ty * 4 + i;
    if (row < M) {
      float4 v = make_float4(acc[i][0], acc[i][1], acc[i][2], acc[i][3]);
      *(float4*)&C[(size_t)row * N + n0 + tx * 4] = v;
    }
  }
}

// ---------------- per-node attention scores s_src/s_dst ----------------
template<int U>
__global__ __launch_bounds__(256) void s_kernel(const float* __restrict__ h, const float* __restrict__ asrc,
                                                const float* __restrict__ adst, float* __restrict__ s_src,
                                                float* __restrict__ s_dst, int n) {
  int node = blockIdx.x * 256 + threadIdx.x;
  if (node >= n) return;
  const float* hp = h + (size_t)node * 8 * U;
#pragma unroll
  for (int hh = 0; hh < 8; ++hh) {
    float ss = 0.f, dd = 0.f;
#pragma unroll
    for (int u = 0; u < U; u += 4) {
      float4 hv = *(const float4*)&hp[hh * U + u];
      float4 av = *(const float4*)&asrc[hh * U + u];
      float4 bv = *(const float4*)&adst[hh * U + u];
      ss += hv.x * av.x + hv.y * av.y + hv.z * av.z + hv.w * av.w;
      dd += hv.x * bv.x + hv.y * bv.y + hv.z * bv.z + hv.w * bv.w;
    }
    s_src[(size_t)node * 8 + hh] = ss;
    s_dst[(size_t)node * 8 + hh] = dd;
  }
}

// ---------------- CSR build ----------------
__global__ void count_kernel(const int2* __restrict__ edges, int* __restrict__ cnt, int E) {
  int e = blockIdx.x * blockDim.x + threadIdx.x;
  if (e < E) atomicAdd(&cnt[edges[e].x], 1);
}

// 3-phase device-wide exclusive scan over cnt[NN] -> row_off, cursor
__global__ __launch_bounds__(256) void scan1_kernel(const int* __restrict__ cnt, int* __restrict__ row_off,
                                                    int* __restrict__ bsum, int n) {
  __shared__ int ts[256];
  const int b = blockIdx.x, tid = threadIdx.x;
  const int base = b * 1024;
  int v[4];
  int s = 0;
#pragma unroll
  for (int j = 0; j < 4; ++j) {
    int i = base + tid * 4 + j;
    v[j] = (i < n) ? cnt[i] : 0;
    s += v[j];
  }
  ts[tid] = s;
  __syncthreads();
  for (int off = 1; off < 256; off <<= 1) {
    int t = (tid >= off) ? ts[tid - off] : 0;
    __syncthreads();
    ts[tid] += t;
    __syncthreads();
  }
  int run = ts[tid] - s;  // exclusive prefix within block
#pragma unroll
  for (int j = 0; j < 4; ++j) {
    int i = base + tid * 4 + j;
    if (i < n) row_off[i] = run;
    run += v[j];
  }
  if (tid == 255) bsum[b] = ts[255];
}

__global__ __launch_bounds__(128) void scan2_kernel(int* __restrict__ bsum, int nb) {
  __shared__ int s[128];
  int tid = threadIdx.x;
  int v = (tid < nb) ? bsum[tid] : 0;
  s[tid] = v;
  __syncthreads();
  for (int off = 1; off < 128; off <<= 1) {
    int t = (tid >= off) ? s[tid - off] : 0;
    __syncthreads();
    s[tid] += t;
    __syncthreads();
  }
  if (tid < nb) bsum[tid] = s[tid] - v;  // exclusive block offsets
}

__global__ __launch_bounds__(256) void scan3_kernel(int* __restrict__ row_off, int* __restrict__ cursor,
                                                    const int* __restrict__ bsum, int n) {
  const int b = blockIdx.x, tid = threadIdx.x;
  const int add = bsum[b];
  const int base = b * 1024;
#pragma unroll
  for (int j = 0; j < 4; ++j) {
    int i = base + tid + j * 256;
    if (i < n) {
      int r = row_off[i] + add;
      row_off[i] = r;
      cursor[i] = r;
    }
  }
  if (b == 0 && tid == 0) row_off[n] = NE;
}

__global__ void scatter_kernel(const int2* __restrict__ edges, int* __restrict__ cursor,
                               int* __restrict__ sorted_src, int E) {
  int e = blockIdx.x * blockDim.x + threadIdx.x;
  if (e < E) {
    int2 ed = edges[e];
    int pos = atomicAdd(&cursor[ed.x], 1);
    sorted_src[pos] = ed.y;
  }
}

// ---------------- layer-1 aggregation: wave per node, lane = (h*8+u) ----------------
__global__ __launch_bounds__(256) void agg1_kernel(const int* __restrict__ row_off, const int* __restrict__ srcs,
                                                   const float* __restrict__ s_src, const float* __restrict__ s_dst,
                                                   const float* __restrict__ h, float* __restrict__ out, int n) {
  int wave = (blockIdx.x * 256 + threadIdx.x) >> 6;
  int lane = threadIdx.x & 63;
  if (wave >= n) return;
  int hh = lane >> 3;
  float sd = s_dst[(size_t)wave * 8 + hh];
  int beg = row_off[wave], end = row_off[wave + 1];
  float acc = 0.f, den = 0.f;
  int src = (beg < end) ? srcs[beg] : 0;
  for (int i = beg; i < end; ++i) {
    int src_next = (i + 1 < end) ? srcs[i + 1] : 0;
    float ssv = s_src[(size_t)src * 8 + hh];
    float hv = h[(size_t)src * 64 + lane];
    float e = sd + ssv;
    e = e > 0.f ? e : 0.2f * e;
    float ex = __expf(e);
    den += ex;
    acc = fmaf(ex, hv, acc);
    src = src_next;
  }
  out[(size_t)wave * 64 + lane] = acc / fmaxf(den, 1e-9f);
}

// ---------------- layer-2 aggregation + head average: lane = (h*8 + o/2) ----------------
__global__ __launch_bounds__(256) void agg2_kernel(const int* __restrict__ row_off, const int* __restrict__ srcs,
                                                   const float* __restrict__ s_src, const float* __restrict__ s_dst,
                                                   const float* __restrict__ h2, float* __restrict__ out, int n) {
  int wave = (blockIdx.x * 256 + threadIdx.x) >> 6;
  int lane = threadIdx.x & 63;
  if (wave >= n) return;
  int hh = lane >> 3, o2 = lane & 7;
  float sd = s_dst[(size_t)wave * 8 + hh];
  int beg = row_off[wave], end = row_off[wave + 1];
  float a0 = 0.f, a1 = 0.f, den = 0.f;
  int src = (beg < end) ? srcs[beg] : 0;
  for (int i = beg; i < end; ++i) {
    int src_next = (i + 1 < end) ? srcs[i + 1] : 0;
    float ssv = s_src[(size_t)src * 8 + hh];
    float2 v = *(const float2*)&h2[(size_t)src * 128 + hh * 16 + o2 * 2];
    float e = sd + ssv;
    e = e > 0.f ? e : 0.2f * e;
    float ex = __expf(e);
    den += ex;
    a0 = fmaf(ex, v.x, a0);
    a1 = fmaf(ex, v.y, a1);
    src = src_next;
  }
  float r0 = a0 / fmaxf(den, 1e-9f);
  float r1 = a1 / fmaxf(den, 1e-9f);
  for (int m = 8; m < 64; m <<= 1) {
    r0 += __shfl_xor(r0, m, 64);
    r1 += __shfl_xor(r1, m, 64);
  }
  if (lane < 8) {
    float2 w = make_float2(r0 * 0.125f, r1 * 0.125f);
    *(float2*)&out[(size_t)wave * 16 + lane * 2] = w;
  }
}

// ---------------- final index gather ----------------
__global__ void gather_kernel(const float* __restrict__ out2, const int* __restrict__ idx,
                              float* __restrict__ out, int ni) {
  int t = blockIdx.x * blockDim.x + threadIdx.x;
  if (t < ni * 4) {
    int i = t >> 2, q = t & 3;
    int node = idx[i];
    *(float4*)&out[(size_t)i * 16 + q * 4] = *(const float4*)&out2[(size_t)node * 16 + q * 4];
  }
}

extern "C" void kernel_launch(void* const* d_in, const int* in_sizes, int n_in,
                              void* d_out, int out_size, void* d_ws, size_t ws_size,
                              hipStream_t stream) {
  const float* x   = (const float*)d_in[0];
  const int2* edges = (const int2*)d_in[1];
  const int* indices = (const int*)d_in[2];
  const float* W1  = (const float*)d_in[3];
  const float* a1s = (const float*)d_in[4];
  const float* a1d = (const float*)d_in[5];
  const float* W2  = (const float*)d_in[6];
  const float* a2s = (const float*)d_in[7];
  const float* a2d = (const float*)d_in[8];
  float* out = (float*)d_out;

  char* ws = (char*)d_ws;
  size_t off = 0;
  auto alloc = [&](size_t bytes) {
    void* p = ws + off;
    off = (off + bytes + 255) & ~(size_t)255;
    return p;
  };
  float* h1    = (float*)alloc((size_t)NN * 64 * 4);   // reused as out2 later
  float* out2  = h1;
  float* s1src = (float*)alloc((size_t)NN * 8 * 4);    // reused for layer 2
  float* s1dst = (float*)alloc((size_t)NN * 8 * 4);
  float* out1  = (float*)alloc((size_t)NN * 64 * 4);
  float* h2    = (float*)alloc((size_t)NN * 128 * 4);
  int* cnt     = (int*)alloc((size_t)NN * 4);
  int* row_off = (int*)alloc(((size_t)NN + 1) * 4);
  int* cursor  = (int*)alloc((size_t)NN * 4);
  int* ssrc    = (int*)alloc((size_t)NE * 4);
  int* bsum    = (int*)alloc(128 * 4);

  hipMemsetAsync(cnt, 0, (size_t)NN * 4, stream);

  dim3 b256(256);
  // layer 1 GEMM: h1 = x @ W1  ([100000,512] x [512,64])
  gemm64<false><<<dim3((NN + 63) / 64, 1), b256, 0, stream>>>(x, W1, h1, NN, 64, 512);
  // scores
  s_kernel<8><<<dim3((NN + 255) / 256), b256, 0, stream>>>(h1, a1s, a1d, s1src, s1dst, NN);
  // CSR build (by dst)
  count_kernel<<<dim3((NE + 255) / 256), b256, 0, stream>>>(edges, cnt, NE);
  scan1_kernel<<<dim3(SCAN_NB), b256, 0, stream>>>(cnt, row_off, bsum, NN);
  scan2_kernel<<<dim3(1), dim3(128), 0, stream>>>(bsum, SCAN_NB);
  scan3_kernel<<<dim3(SCAN_NB), b256, 0, stream>>>(row_off, cursor, bsum, NN);
  scatter_kernel<<<dim3((NE + 255) / 256), b256, 0, stream>>>(edges, cursor, ssrc, NE);
  // layer 1 aggregation
  agg1_kernel<<<dim3(NN / 4), b256, 0, stream>>>(row_off, ssrc, s1src, s1dst, h1, out1, NN);
  // layer 2 GEMM with fused ELU on input: h2 = elu(out1) @ W2  ([100000,64] x [64,128])
  gemm64<true><<<dim3((NN + 63) / 64, 2), b256, 0, stream>>>(out1, W2, h2, NN, 128, 64);
  // layer 2 scores (reuse s buffers)
  s_kernel<16><<<dim3((NN + 255) / 256), b256, 0, stream>>>(h2, a2s, a2d, s1src, s1dst, NN);
  // layer 2 aggregation + head average
  agg2_kernel<<<dim3(NN / 4), b256, 0, stream>>>(row_off, ssrc, s1src, s1dst, h2, out2, NN);
  // final gather
  gather_kernel<<<dim3((NIDX * 4 + 255) / 256), b256, 0, stream>>>(out2, indices, out, NIDX);
}

// Round 3
// 565.487 us; speedup vs baseline: 1.6137x; 1.2311x over previous
//
#include <hip/hip_runtime.h>

#define NN 100000
#define NE 1600000
#define DF 512
#define NIDX 10000
#define SCAN_NB ((NN + 1023) / 1024)   // 98 blocks, 1024 elements each

__device__ __forceinline__ float eluf(float x) { return x > 0.f ? x : expm1f(x); }
__device__ __forceinline__ float lrelu(float x) { return x > 0.f ? x : 0.2f * x; }

// ---------------- GEMM: C[M,N] = A[M,K] @ B[K,N], BM=BN=64, BK=32 ----------------
template<bool ELU_A>
__global__ __launch_bounds__(256) void gemm64(const float* __restrict__ A, const float* __restrict__ B,
                                              float* __restrict__ C, int M, int N, int K) {
  __shared__ float As[32][68];
  __shared__ float Bs[32][68];
  const int tid = threadIdx.x;
  const int m0 = blockIdx.x * 64;
  const int n0 = blockIdx.y * 64;
  const int tx = tid & 15, ty = tid >> 4;
  float acc[4][4] = {};
  for (int k0 = 0; k0 < K; k0 += 32) {
    for (int j = tid; j < 512; j += 256) {  // A tile: 64 rows x 32 cols, transposed into As[k][m]
      int r = j >> 3, kq = j & 7;
      int row = m0 + r;
      float4 v = make_float4(0.f, 0.f, 0.f, 0.f);
      if (row < M) v = *(const float4*)&A[(size_t)row * K + k0 + kq * 4];
      if (ELU_A) { v.x = eluf(v.x); v.y = eluf(v.y); v.z = eluf(v.z); v.w = eluf(v.w); }
      As[kq * 4 + 0][r] = v.x; As[kq * 4 + 1][r] = v.y;
      As[kq * 4 + 2][r] = v.z; As[kq * 4 + 3][r] = v.w;
    }
    for (int j = tid; j < 512; j += 256) {  // B tile: 32 rows x 64 cols
      int kr = j >> 4, nq = j & 15;
      *(float4*)&Bs[kr][nq * 4] = *(const float4*)&B[(size_t)(k0 + kr) * N + n0 + nq * 4];
    }
    __syncthreads();
#pragma unroll
    for (int kk = 0; kk < 32; ++kk) {
      float4 a4 = *(const float4*)&As[kk][ty * 4];
      float4 b4 = *(const float4*)&Bs[kk][tx * 4];
      float av[4] = {a4.x, a4.y, a4.z, a4.w};
      float bv[4] = {b4.x, b4.y, b4.z, b4.w};
#pragma unroll
      for (int i = 0; i < 4; ++i)
#pragma unroll
        for (int jj = 0; jj < 4; ++jj)
          acc[i][jj] = fmaf(av[i], bv[jj], acc[i][jj]);
    }
    __syncthreads();
  }
#pragma unroll
  for (int i = 0; i < 4; ++i) {
    int row = m0 + ty * 4 + i;
    if (row < M) {
      float4 v = make_float4(acc[i][0], acc[i][1], acc[i][2], acc[i][3]);
      *(float4*)&C[(size_t)row * N + n0 + tx * 4] = v;
    }
  }
}

// ---------------- per-node attention scores s_src/s_dst ----------------
template<int U>
__global__ __launch_bounds__(256) void s_kernel(const float* __restrict__ h, const float* __restrict__ asrc,
                                                const float* __restrict__ adst, float* __restrict__ s_src,
                                                float* __restrict__ s_dst, int n) {
  int node = blockIdx.x * 256 + threadIdx.x;
  if (node >= n) return;
  const float* hp = h + (size_t)node * 8 * U;
#pragma unroll
  for (int hh = 0; hh < 8; ++hh) {
    float ss = 0.f, dd = 0.f;
#pragma unroll
    for (int u = 0; u < U; u += 4) {
      float4 hv = *(const float4*)&hp[hh * U + u];
      float4 av = *(const float4*)&asrc[hh * U + u];
      float4 bv = *(const float4*)&adst[hh * U + u];
      ss += hv.x * av.x + hv.y * av.y + hv.z * av.z + hv.w * av.w;
      dd += hv.x * bv.x + hv.y * bv.y + hv.z * bv.z + hv.w * bv.w;
    }
    s_src[(size_t)node * 8 + hh] = ss;
    s_dst[(size_t)node * 8 + hh] = dd;
  }
}

// ---------------- CSR build ----------------
__global__ void count_kernel(const int2* __restrict__ edges, int* __restrict__ cnt, int E) {
  int e = blockIdx.x * blockDim.x + threadIdx.x;
  if (e < E) atomicAdd(&cnt[edges[e].x], 1);
}

// 3-phase device-wide exclusive scan over cnt[NN] -> row_off, cursor
__global__ __launch_bounds__(256) void scan1_kernel(const int* __restrict__ cnt, int* __restrict__ row_off,
                                                    int* __restrict__ bsum, int n) {
  __shared__ int ts[256];
  const int b = blockIdx.x, tid = threadIdx.x;
  const int base = b * 1024;
  int v[4];
  int s = 0;
#pragma unroll
  for (int j = 0; j < 4; ++j) {
    int i = base + tid * 4 + j;
    v[j] = (i < n) ? cnt[i] : 0;
    s += v[j];
  }
  ts[tid] = s;
  __syncthreads();
  for (int off = 1; off < 256; off <<= 1) {
    int t = (tid >= off) ? ts[tid - off] : 0;
    __syncthreads();
    ts[tid] += t;
    __syncthreads();
  }
  int run = ts[tid] - s;  // exclusive prefix within block
#pragma unroll
  for (int j = 0; j < 4; ++j) {
    int i = base + tid * 4 + j;
    if (i < n) row_off[i] = run;
    run += v[j];
  }
  if (tid == 255) bsum[b] = ts[255];
}

__global__ __launch_bounds__(128) void scan2_kernel(int* __restrict__ bsum, int nb) {
  __shared__ int s[128];
  int tid = threadIdx.x;
  int v = (tid < nb) ? bsum[tid] : 0;
  s[tid] = v;
  __syncthreads();
  for (int off = 1; off < 128; off <<= 1) {
    int t = (tid >= off) ? s[tid - off] : 0;
    __syncthreads();
    s[tid] += t;
    __syncthreads();
  }
  if (tid < nb) bsum[tid] = s[tid] - v;  // exclusive block offsets
}

__global__ __launch_bounds__(256) void scan3_kernel(int* __restrict__ row_off, int* __restrict__ cursor,
                                                    const int* __restrict__ bsum, int n) {
  const int b = blockIdx.x, tid = threadIdx.x;
  const int add = bsum[b];
  const int base = b * 1024;
#pragma unroll
  for (int j = 0; j < 4; ++j) {
    int i = base + tid + j * 256;
    if (i < n) {
      int r = row_off[i] + add;
      row_off[i] = r;
      cursor[i] = r;
    }
  }
  if (b == 0 && tid == 0) row_off[n] = NE;
}

__global__ void scatter_kernel(const int2* __restrict__ edges, int* __restrict__ cursor,
                               int* __restrict__ sorted_src, int E) {
  int e = blockIdx.x * blockDim.x + threadIdx.x;
  if (e < E) {
    int2 ed = edges[e];
    int pos = atomicAdd(&cursor[ed.x], 1);
    sorted_src[pos] = ed.y;
  }
}

// ---------------- layer-1 aggregation: wave per node, lane = (h*8+u), 4-edge unroll ----------------
__global__ __launch_bounds__(256) void agg1_kernel(const int* __restrict__ row_off, const int* __restrict__ srcs,
                                                   const float* __restrict__ s_src, const float* __restrict__ s_dst,
                                                   const float* __restrict__ h, float* __restrict__ out, int n) {
  int wave = (blockIdx.x * 256 + threadIdx.x) >> 6;
  int lane = threadIdx.x & 63;
  if (wave >= n) return;
  int hh = lane >> 3;
  float sd = s_dst[(size_t)wave * 8 + hh];
  int beg = row_off[wave], end = row_off[wave + 1];
  float acc = 0.f, den = 0.f;
  int i = beg;
  for (; i + 4 <= end; i += 4) {
    int s0 = srcs[i], s1 = srcs[i + 1], s2 = srcs[i + 2], s3 = srcs[i + 3];
    float e0 = s_src[(size_t)s0 * 8 + hh];
    float e1 = s_src[(size_t)s1 * 8 + hh];
    float e2 = s_src[(size_t)s2 * 8 + hh];
    float e3 = s_src[(size_t)s3 * 8 + hh];
    float h0 = h[(size_t)s0 * 64 + lane];
    float h1 = h[(size_t)s1 * 64 + lane];
    float h2 = h[(size_t)s2 * 64 + lane];
    float h3 = h[(size_t)s3 * 64 + lane];
    float x0 = __expf(lrelu(sd + e0));
    float x1 = __expf(lrelu(sd + e1));
    float x2 = __expf(lrelu(sd + e2));
    float x3 = __expf(lrelu(sd + e3));
    den += (x0 + x1) + (x2 + x3);
    acc = fmaf(x0, h0, fmaf(x1, h1, fmaf(x2, h2, fmaf(x3, h3, acc))));
  }
  for (; i < end; ++i) {
    int s0 = srcs[i];
    float x0 = __expf(lrelu(sd + s_src[(size_t)s0 * 8 + hh]));
    den += x0;
    acc = fmaf(x0, h[(size_t)s0 * 64 + lane], acc);
  }
  out[(size_t)wave * 64 + lane] = acc / fmaxf(den, 1e-9f);
}

// ---------------- layer-2 aggregation + head average: lane = (h*8 + o/2), 4-edge unroll ----------------
__global__ __launch_bounds__(256) void agg2_kernel(const int* __restrict__ row_off, const int* __restrict__ srcs,
                                                   const float* __restrict__ s_src, const float* __restrict__ s_dst,
                                                   const float* __restrict__ h2, float* __restrict__ out, int n) {
  int wave = (blockIdx.x * 256 + threadIdx.x) >> 6;
  int lane = threadIdx.x & 63;
  if (wave >= n) return;
  int hh = lane >> 3, o2 = lane & 7;
  float sd = s_dst[(size_t)wave * 8 + hh];
  int beg = row_off[wave], end = row_off[wave + 1];
  float a0 = 0.f, a1 = 0.f, den = 0.f;
  int i = beg;
  for (; i + 4 <= end; i += 4) {
    int s0 = srcs[i], s1 = srcs[i + 1], s2 = srcs[i + 2], s3 = srcs[i + 3];
    float e0 = s_src[(size_t)s0 * 8 + hh];
    float e1 = s_src[(size_t)s1 * 8 + hh];
    float e2 = s_src[(size_t)s2 * 8 + hh];
    float e3 = s_src[(size_t)s3 * 8 + hh];
    float2 v0 = *(const float2*)&h2[(size_t)s0 * 128 + hh * 16 + o2 * 2];
    float2 v1 = *(const float2*)&h2[(size_t)s1 * 128 + hh * 16 + o2 * 2];
    float2 v2 = *(const float2*)&h2[(size_t)s2 * 128 + hh * 16 + o2 * 2];
    float2 v3 = *(const float2*)&h2[(size_t)s3 * 128 + hh * 16 + o2 * 2];
    float x0 = __expf(lrelu(sd + e0));
    float x1 = __expf(lrelu(sd + e1));
    float x2 = __expf(lrelu(sd + e2));
    float x3 = __expf(lrelu(sd + e3));
    den += (x0 + x1) + (x2 + x3);
    a0 = fmaf(x0, v0.x, fmaf(x1, v1.x, fmaf(x2, v2.x, fmaf(x3, v3.x, a0))));
    a1 = fmaf(x0, v0.y, fmaf(x1, v1.y, fmaf(x2, v2.y, fmaf(x3, v3.y, a1))));
  }
  for (; i < end; ++i) {
    int s0 = srcs[i];
    float x0 = __expf(lrelu(sd + s_src[(size_t)s0 * 8 + hh]));
    float2 v0 = *(const float2*)&h2[(size_t)s0 * 128 + hh * 16 + o2 * 2];
    den += x0;
    a0 = fmaf(x0, v0.x, a0);
    a1 = fmaf(x0, v0.y, a1);
  }
  float r0 = a0 / fmaxf(den, 1e-9f);
  float r1 = a1 / fmaxf(den, 1e-9f);
  for (int m = 8; m < 64; m <<= 1) {
    r0 += __shfl_xor(r0, m, 64);
    r1 += __shfl_xor(r1, m, 64);
  }
  if (lane < 8) {
    float2 w = make_float2(r0 * 0.125f, r1 * 0.125f);
    *(float2*)&out[(size_t)wave * 16 + lane * 2] = w;
  }
}

// ---------------- final index gather ----------------
__global__ void gather_kernel(const float* __restrict__ out2, const int* __restrict__ idx,
                              float* __restrict__ out, int ni) {
  int t = blockIdx.x * blockDim.x + threadIdx.x;
  if (t < ni * 4) {
    int i = t >> 2, q = t & 3;
    int node = idx[i];
    *(float4*)&out[(size_t)i * 16 + q * 4] = *(const float4*)&out2[(size_t)node * 16 + q * 4];
  }
}

extern "C" void kernel_launch(void* const* d_in, const int* in_sizes, int n_in,
                              void* d_out, int out_size, void* d_ws, size_t ws_size,
                              hipStream_t stream) {
  const float* x   = (const float*)d_in[0];
  const int2* edges = (const int2*)d_in[1];
  const int* indices = (const int*)d_in[2];
  const float* W1  = (const float*)d_in[3];
  const float* a1s = (const float*)d_in[4];
  const float* a1d = (const float*)d_in[5];
  const float* W2  = (const float*)d_in[6];
  const float* a2s = (const float*)d_in[7];
  const float* a2d = (const float*)d_in[8];
  float* out = (float*)d_out;

  char* ws = (char*)d_ws;
  size_t off = 0;
  auto alloc = [&](size_t bytes) {
    void* p = ws + off;
    off = (off + bytes + 255) & ~(size_t)255;
    return p;
  };
  float* h1    = (float*)alloc((size_t)NN * 64 * 4);   // reused as out2 later
  float* out2  = h1;
  float* s1src = (float*)alloc((size_t)NN * 8 * 4);    // reused for layer 2
  float* s1dst = (float*)alloc((size_t)NN * 8 * 4);
  float* out1  = (float*)alloc((size_t)NN * 64 * 4);
  float* h2    = (float*)alloc((size_t)NN * 128 * 4);
  int* cnt     = (int*)alloc((size_t)NN * 4);
  int* row_off = (int*)alloc(((size_t)NN + 1) * 4);
  int* cursor  = (int*)alloc((size_t)NN * 4);
  int* ssrc    = (int*)alloc((size_t)NE * 4);
  int* bsum    = (int*)alloc(128 * 4);

  hipMemsetAsync(cnt, 0, (size_t)NN * 4, stream);

  dim3 b256(256);
  // layer 1 GEMM: h1 = x @ W1  ([100000,512] x [512,64])
  gemm64<false><<<dim3((NN + 63) / 64, 1), b256, 0, stream>>>(x, W1, h1, NN, 64, 512);
  // scores
  s_kernel<8><<<dim3((NN + 255) / 256), b256, 0, stream>>>(h1, a1s, a1d, s1src, s1dst, NN);
  // CSR build (by dst)
  count_kernel<<<dim3((NE + 255) / 256), b256, 0, stream>>>(edges, cnt, NE);
  scan1_kernel<<<dim3(SCAN_NB), b256, 0, stream>>>(cnt, row_off, bsum, NN);
  scan2_kernel<<<dim3(1), dim3(128), 0, stream>>>(bsum, SCAN_NB);
  scan3_kernel<<<dim3(SCAN_NB), b256, 0, stream>>>(row_off, cursor, bsum, NN);
  scatter_kernel<<<dim3((NE + 255) / 256), b256, 0, stream>>>(edges, cursor, ssrc, NE);
  // layer 1 aggregation
  agg1_kernel<<<dim3(NN / 4), b256, 0, stream>>>(row_off, ssrc, s1src, s1dst, h1, out1, NN);
  // layer 2 GEMM with fused ELU on input: h2 = elu(out1) @ W2  ([100000,64] x [64,128])
  gemm64<true><<<dim3((NN + 63) / 64, 2), b256, 0, stream>>>(out1, W2, h2, NN, 128, 64);
  // layer 2 scores (reuse s buffers)
  s_kernel<16><<<dim3((NN + 255) / 256), b256, 0, stream>>>(h2, a2s, a2d, s1src, s1dst, NN);
  // layer 2 aggregation + head average
  agg2_kernel<<<dim3(NN / 4), b256, 0, stream>>>(row_off, ssrc, s1src, s1dst, h2, out2, NN);
  // final gather
  gather_kernel<<<dim3((NIDX * 4 + 255) / 256), b256, 0, stream>>>(out2, indices, out, NIDX);
}

// Round 4
// 515.192 us; speedup vs baseline: 1.7712x; 1.0976x over previous
//
#include <hip/hip_runtime.h>
#include <hip/hip_bf16.h>

#define NN 100000
#define NE 1600000
#define DF 512
#define NIDX 10000
#define SCAN_NB ((NN + 1023) / 1024)   // 98 blocks, 1024 elements each

__device__ __forceinline__ float eluf(float x) { return x > 0.f ? x : expm1f(x); }
__device__ __forceinline__ float lrelu(float x) { return x > 0.f ? x : 0.2f * x; }

// ---------------- GEMM: C[M,N] = A[M,K] @ B[K,N], BM=BN=64, BK=32 ----------------
// Optionally writes an f32 copy (C) and/or a bf16 copy (Cb).
template<bool ELU_A, bool WRITE_F32, bool WRITE_BF16>
__global__ __launch_bounds__(256) void gemm64(const float* __restrict__ A, const float* __restrict__ B,
                                              float* __restrict__ C, __hip_bfloat162* __restrict__ Cb,
                                              int M, int N, int K) {
  __shared__ float As[32][68];
  __shared__ float Bs[32][68];
  const int tid = threadIdx.x;
  const int m0 = blockIdx.x * 64;
  const int n0 = blockIdx.y * 64;
  const int tx = tid & 15, ty = tid >> 4;
  float acc[4][4] = {};
  for (int k0 = 0; k0 < K; k0 += 32) {
    for (int j = tid; j < 512; j += 256) {  // A tile: 64 rows x 32 cols, transposed into As[k][m]
      int r = j >> 3, kq = j & 7;
      int row = m0 + r;
      float4 v = make_float4(0.f, 0.f, 0.f, 0.f);
      if (row < M) v = *(const float4*)&A[(size_t)row * K + k0 + kq * 4];
      if (ELU_A) { v.x = eluf(v.x); v.y = eluf(v.y); v.z = eluf(v.z); v.w = eluf(v.w); }
      As[kq * 4 + 0][r] = v.x; As[kq * 4 + 1][r] = v.y;
      As[kq * 4 + 2][r] = v.z; As[kq * 4 + 3][r] = v.w;
    }
    for (int j = tid; j < 512; j += 256) {  // B tile: 32 rows x 64 cols
      int kr = j >> 4, nq = j & 15;
      *(float4*)&Bs[kr][nq * 4] = *(const float4*)&B[(size_t)(k0 + kr) * N + n0 + nq * 4];
    }
    __syncthreads();
#pragma unroll
    for (int kk = 0; kk < 32; ++kk) {
      float4 a4 = *(const float4*)&As[kk][ty * 4];
      float4 b4 = *(const float4*)&Bs[kk][tx * 4];
      float av[4] = {a4.x, a4.y, a4.z, a4.w};
      float bv[4] = {b4.x, b4.y, b4.z, b4.w};
#pragma unroll
      for (int i = 0; i < 4; ++i)
#pragma unroll
        for (int jj = 0; jj < 4; ++jj)
          acc[i][jj] = fmaf(av[i], bv[jj], acc[i][jj]);
    }
    __syncthreads();
  }
#pragma unroll
  for (int i = 0; i < 4; ++i) {
    int row = m0 + ty * 4 + i;
    if (row < M) {
      if (WRITE_F32) {
        float4 v = make_float4(acc[i][0], acc[i][1], acc[i][2], acc[i][3]);
        *(float4*)&C[(size_t)row * N + n0 + tx * 4] = v;
      }
      if (WRITE_BF16) {
        __hip_bfloat162 p0, p1;
        p0.x = __float2bfloat16(acc[i][0]); p0.y = __float2bfloat16(acc[i][1]);
        p1.x = __float2bfloat16(acc[i][2]); p1.y = __float2bfloat16(acc[i][3]);
        size_t base = ((size_t)row * N + n0 + tx * 4) >> 1;
        Cb[base] = p0; Cb[base + 1] = p1;
      }
    }
  }
}

// ---------------- per-node attention scores (f32 h) ----------------
template<int U>
__global__ __launch_bounds__(256) void s_kernel(const float* __restrict__ h, const float* __restrict__ asrc,
                                                const float* __restrict__ adst, float* __restrict__ s_src,
                                                float* __restrict__ s_dst, int n) {
  int node = blockIdx.x * 256 + threadIdx.x;
  if (node >= n) return;
  const float* hp = h + (size_t)node * 8 * U;
#pragma unroll
  for (int hh = 0; hh < 8; ++hh) {
    float ss = 0.f, dd = 0.f;
#pragma unroll
    for (int u = 0; u < U; u += 4) {
      float4 hv = *(const float4*)&hp[hh * U + u];
      float4 av = *(const float4*)&asrc[hh * U + u];
      float4 bv = *(const float4*)&adst[hh * U + u];
      ss += hv.x * av.x + hv.y * av.y + hv.z * av.z + hv.w * av.w;
      dd += hv.x * bv.x + hv.y * bv.y + hv.z * bv.z + hv.w * bv.w;
    }
    s_src[(size_t)node * 8 + hh] = ss;
    s_dst[(size_t)node * 8 + hh] = dd;
  }
}

// ---------------- per-node attention scores (bf16 h, U=16) ----------------
__global__ __launch_bounds__(256) void s2_kernel(const __hip_bfloat162* __restrict__ h, const float* __restrict__ asrc,
                                                 const float* __restrict__ adst, float* __restrict__ s_src,
                                                 float* __restrict__ s_dst, int n) {
  int node = blockIdx.x * 256 + threadIdx.x;
  if (node >= n) return;
  const __hip_bfloat162* hp = h + (size_t)node * 64;  // 128 bf16 = 64 pairs
#pragma unroll
  for (int hh = 0; hh < 8; ++hh) {
    float ss = 0.f, dd = 0.f;
#pragma unroll
    for (int u2 = 0; u2 < 8; ++u2) {
      float2 f = __bfloat1622float2(hp[hh * 8 + u2]);
      float a0 = asrc[hh * 16 + u2 * 2], a1 = asrc[hh * 16 + u2 * 2 + 1];
      float b0 = adst[hh * 16 + u2 * 2], b1 = adst[hh * 16 + u2 * 2 + 1];
      ss += f.x * a0 + f.y * a1;
      dd += f.x * b0 + f.y * b1;
    }
    s_src[(size_t)node * 8 + hh] = ss;
    s_dst[(size_t)node * 8 + hh] = dd;
  }
}

// ---------------- CSR build ----------------
__global__ void count_kernel(const int2* __restrict__ edges, int* __restrict__ cnt, int E) {
  int e = blockIdx.x * blockDim.x + threadIdx.x;
  if (e < E) atomicAdd(&cnt[edges[e].x], 1);
}

__global__ __launch_bounds__(256) void scan1_kernel(const int* __restrict__ cnt, int* __restrict__ row_off,
                                                    int* __restrict__ bsum, int n) {
  __shared__ int ts[256];
  const int b = blockIdx.x, tid = threadIdx.x;
  const int base = b * 1024;
  int v[4];
  int s = 0;
#pragma unroll
  for (int j = 0; j < 4; ++j) {
    int i = base + tid * 4 + j;
    v[j] = (i < n) ? cnt[i] : 0;
    s += v[j];
  }
  ts[tid] = s;
  __syncthreads();
  for (int off = 1; off < 256; off <<= 1) {
    int t = (tid >= off) ? ts[tid - off] : 0;
    __syncthreads();
    ts[tid] += t;
    __syncthreads();
  }
  int run = ts[tid] - s;  // exclusive prefix within block
#pragma unroll
  for (int j = 0; j < 4; ++j) {
    int i = base + tid * 4 + j;
    if (i < n) row_off[i] = run;
    run += v[j];
  }
  if (tid == 255) bsum[b] = ts[255];
}

__global__ __launch_bounds__(128) void scan2_kernel(int* __restrict__ bsum, int nb) {
  __shared__ int s[128];
  int tid = threadIdx.x;
  int v = (tid < nb) ? bsum[tid] : 0;
  s[tid] = v;
  __syncthreads();
  for (int off = 1; off < 128; off <<= 1) {
    int t = (tid >= off) ? s[tid - off] : 0;
    __syncthreads();
    s[tid] += t;
    __syncthreads();
  }
  if (tid < nb) bsum[tid] = s[tid] - v;  // exclusive block offsets
}

__global__ __launch_bounds__(256) void scan3_kernel(int* __restrict__ row_off, int* __restrict__ cursor,
                                                    const int* __restrict__ bsum, int n) {
  const int b = blockIdx.x, tid = threadIdx.x;
  const int add = bsum[b];
  const int base = b * 1024;
#pragma unroll
  for (int j = 0; j < 4; ++j) {
    int i = base + tid + j * 256;
    if (i < n) {
      int r = row_off[i] + add;
      row_off[i] = r;
      cursor[i] = r;
    }
  }
  if (b == 0 && tid == 0) row_off[n] = NE;
}

__global__ void scatter_kernel(const int2* __restrict__ edges, int* __restrict__ cursor,
                               int* __restrict__ sorted_src, int E) {
  int e = blockIdx.x * blockDim.x + threadIdx.x;
  if (e < E) {
    int2 ed = edges[e];
    int pos = atomicAdd(&cursor[ed.x], 1);
    sorted_src[pos] = ed.y;
  }
}

// ---------------- layer-1 aggregation: wave per node, lane = (h*8+u), 4-edge unroll, bf16 values ----------------
__global__ __launch_bounds__(256) void agg1_kernel(const int* __restrict__ row_off, const int* __restrict__ srcs,
                                                   const float* __restrict__ s_src, const float* __restrict__ s_dst,
                                                   const __hip_bfloat16* __restrict__ hb, float* __restrict__ out, int n) {
  int wave = (blockIdx.x * 256 + threadIdx.x) >> 6;
  int lane = threadIdx.x & 63;
  if (wave >= n) return;
  int hh = lane >> 3;
  float sd = s_dst[(size_t)wave * 8 + hh];
  int beg = row_off[wave], end = row_off[wave + 1];
  float acc = 0.f, den = 0.f;
  int i = beg;
  for (; i + 4 <= end; i += 4) {
    int s0 = srcs[i], s1 = srcs[i + 1], s2 = srcs[i + 2], s3 = srcs[i + 3];
    float e0 = s_src[(size_t)s0 * 8 + hh];
    float e1 = s_src[(size_t)s1 * 8 + hh];
    float e2 = s_src[(size_t)s2 * 8 + hh];
    float e3 = s_src[(size_t)s3 * 8 + hh];
    float h0 = __bfloat162float(hb[(size_t)s0 * 64 + lane]);
    float h1 = __bfloat162float(hb[(size_t)s1 * 64 + lane]);
    float h2 = __bfloat162float(hb[(size_t)s2 * 64 + lane]);
    float h3 = __bfloat162float(hb[(size_t)s3 * 64 + lane]);
    float x0 = __expf(lrelu(sd + e0));
    float x1 = __expf(lrelu(sd + e1));
    float x2 = __expf(lrelu(sd + e2));
    float x3 = __expf(lrelu(sd + e3));
    den += (x0 + x1) + (x2 + x3);
    acc = fmaf(x0, h0, fmaf(x1, h1, fmaf(x2, h2, fmaf(x3, h3, acc))));
  }
  for (; i < end; ++i) {
    int s0 = srcs[i];
    float x0 = __expf(lrelu(sd + s_src[(size_t)s0 * 8 + hh]));
    den += x0;
    acc = fmaf(x0, __bfloat162float(hb[(size_t)s0 * 64 + lane]), acc);
  }
  out[(size_t)wave * 64 + lane] = acc / fmaxf(den, 1e-9f);
}

// ---------------- layer-2 aggregation + head average: lane = (h*8 + o/2), 4-edge unroll, bf16 values ----------------
__global__ __launch_bounds__(256) void agg2_kernel(const int* __restrict__ row_off, const int* __restrict__ srcs,
                                                   const float* __restrict__ s_src, const float* __restrict__ s_dst,
                                                   const __hip_bfloat162* __restrict__ h2b, float* __restrict__ out, int n) {
  int wave = (blockIdx.x * 256 + threadIdx.x) >> 6;
  int lane = threadIdx.x & 63;
  if (wave >= n) return;
  int hh = lane >> 3, o2 = lane & 7;
  float sd = s_dst[(size_t)wave * 8 + hh];
  int beg = row_off[wave], end = row_off[wave + 1];
  float a0 = 0.f, a1 = 0.f, den = 0.f;
  int i = beg;
  for (; i + 4 <= end; i += 4) {
    int s0 = srcs[i], s1 = srcs[i + 1], s2 = srcs[i + 2], s3 = srcs[i + 3];
    float e0 = s_src[(size_t)s0 * 8 + hh];
    float e1 = s_src[(size_t)s1 * 8 + hh];
    float e2 = s_src[(size_t)s2 * 8 + hh];
    float e3 = s_src[(size_t)s3 * 8 + hh];
    float2 v0 = __bfloat1622float2(h2b[(size_t)s0 * 64 + hh * 8 + o2]);
    float2 v1 = __bfloat1622float2(h2b[(size_t)s1 * 64 + hh * 8 + o2]);
    float2 v2 = __bfloat1622float2(h2b[(size_t)s2 * 64 + hh * 8 + o2]);
    float2 v3 = __bfloat1622float2(h2b[(size_t)s3 * 64 + hh * 8 + o2]);
    float x0 = __expf(lrelu(sd + e0));
    float x1 = __expf(lrelu(sd + e1));
    float x2 = __expf(lrelu(sd + e2));
    float x3 = __expf(lrelu(sd + e3));
    den += (x0 + x1) + (x2 + x3);
    a0 = fmaf(x0, v0.x, fmaf(x1, v1.x, fmaf(x2, v2.x, fmaf(x3, v3.x, a0))));
    a1 = fmaf(x0, v0.y, fmaf(x1, v1.y, fmaf(x2, v2.y, fmaf(x3, v3.y, a1))));
  }
  for (; i < end; ++i) {
    int s0 = srcs[i];
    float x0 = __expf(lrelu(sd + s_src[(size_t)s0 * 8 + hh]));
    float2 v0 = __bfloat1622float2(h2b[(size_t)s0 * 64 + hh * 8 + o2]);
    den += x0;
    a0 = fmaf(x0, v0.x, a0);
    a1 = fmaf(x0, v0.y, a1);
  }
  float r0 = a0 / fmaxf(den, 1e-9f);
  float r1 = a1 / fmaxf(den, 1e-9f);
  for (int m = 8; m < 64; m <<= 1) {
    r0 += __shfl_xor(r0, m, 64);
    r1 += __shfl_xor(r1, m, 64);
  }
  if (lane < 8) {
    float2 w = make_float2(r0 * 0.125f, r1 * 0.125f);
    *(float2*)&out[(size_t)wave * 16 + lane * 2] = w;
  }
}

// ---------------- final index gather ----------------
__global__ void gather_kernel(const float* __restrict__ out2, const int* __restrict__ idx,
                              float* __restrict__ out, int ni) {
  int t = blockIdx.x * blockDim.x + threadIdx.x;
  if (t < ni * 4) {
    int i = t >> 2, q = t & 3;
    int node = idx[i];
    *(float4*)&out[(size_t)i * 16 + q * 4] = *(const float4*)&out2[(size_t)node * 16 + q * 4];
  }
}

extern "C" void kernel_launch(void* const* d_in, const int* in_sizes, int n_in,
                              void* d_out, int out_size, void* d_ws, size_t ws_size,
                              hipStream_t stream) {
  const float* x   = (const float*)d_in[0];
  const int2* edges = (const int2*)d_in[1];
  const int* indices = (const int*)d_in[2];
  const float* W1  = (const float*)d_in[3];
  const float* a1s = (const float*)d_in[4];
  const float* a1d = (const float*)d_in[5];
  const float* W2  = (const float*)d_in[6];
  const float* a2s = (const float*)d_in[7];
  const float* a2d = (const float*)d_in[8];
  float* out = (float*)d_out;

  char* ws = (char*)d_ws;
  size_t off = 0;
  auto alloc = [&](size_t bytes) {
    void* p = ws + off;
    off = (off + bytes + 255) & ~(size_t)255;
    return p;
  };
  float* h1    = (float*)alloc((size_t)NN * 64 * 4);     // f32 h1 (scores); reused as out2 at the end
  float* out2  = h1;
  float* s1src = (float*)alloc((size_t)NN * 8 * 4);      // reused for layer 2
  float* s1dst = (float*)alloc((size_t)NN * 8 * 4);
  float* out1  = (float*)alloc((size_t)NN * 64 * 4);
  __hip_bfloat16*  h1b = (__hip_bfloat16*)alloc((size_t)NN * 64 * 2);   // bf16 h1 (agg values)
  __hip_bfloat162* h2b = (__hip_bfloat162*)alloc((size_t)NN * 128 * 2); // bf16 h2 (scores + agg values)
  int* cnt     = (int*)alloc((size_t)NN * 4);
  int* row_off = (int*)alloc(((size_t)NN + 1) * 4);
  int* cursor  = (int*)alloc((size_t)NN * 4);
  int* ssrc    = (int*)alloc((size_t)NE * 4);
  int* bsum    = (int*)alloc(128 * 4);

  hipMemsetAsync(cnt, 0, (size_t)NN * 4, stream);

  dim3 b256(256);
  // layer 1 GEMM: h1 = x @ W1 (f32 for scores + bf16 copy for gather)
  gemm64<false, true, true><<<dim3((NN + 63) / 64, 1), b256, 0, stream>>>(x, W1, h1, (__hip_bfloat162*)h1b, NN, 64, 512);
  // layer-1 scores from f32 h1 (error-sensitive path stays f32)
  s_kernel<8><<<dim3((NN + 255) / 256), b256, 0, stream>>>(h1, a1s, a1d, s1src, s1dst, NN);
  // CSR build (by dst)
  count_kernel<<<dim3((NE + 255) / 256), b256, 0, stream>>>(edges, cnt, NE);
  scan1_kernel<<<dim3(SCAN_NB), b256, 0, stream>>>(cnt, row_off, bsum, NN);
  scan2_kernel<<<dim3(1), dim3(128), 0, stream>>>(bsum, SCAN_NB);
  scan3_kernel<<<dim3(SCAN_NB), b256, 0, stream>>>(row_off, cursor, bsum, NN);
  scatter_kernel<<<dim3((NE + 255) / 256), b256, 0, stream>>>(edges, cursor, ssrc, NE);
  // layer 1 aggregation (bf16 value gather)
  agg1_kernel<<<dim3(NN / 4), b256, 0, stream>>>(row_off, ssrc, s1src, s1dst, h1b, out1, NN);
  // layer 2 GEMM with fused ELU on input: h2 (bf16 only) = elu(out1) @ W2
  gemm64<true, false, true><<<dim3((NN + 63) / 64, 2), b256, 0, stream>>>(out1, W2, nullptr, h2b, NN, 128, 64);
  // layer 2 scores from bf16 h2
  s2_kernel<<<dim3((NN + 255) / 256), b256, 0, stream>>>(h2b, a2s, a2d, s1src, s1dst, NN);
  // layer 2 aggregation + head average (bf16 value gather)
  agg2_kernel<<<dim3(NN / 4), b256, 0, stream>>>(row_off, ssrc, s1src, s1dst, h2b, out2, NN);
  // final gather
  gather_kernel<<<dim3((NIDX * 4 + 255) / 256), b256, 0, stream>>>(out2, indices, out, NIDX);
}

// Round 5
// 344.060 us; speedup vs baseline: 2.6522x; 1.4974x over previous
//
#include <hip/hip_runtime.h>
#include <hip/hip_bf16.h>

#define NN 100000
#define NE 1600000
#define DF 512
#define NIDX 10000

#define NBKT 512
#define BKT_W 196                 // ceil(100000/512); 512*196 = 100352 >= NN
#define EDGES_PER_BKT_BLK 3125    // NE / 512 exactly

typedef __attribute__((ext_vector_type(8))) short short8v;
typedef __attribute__((ext_vector_type(4))) float float4v;

__device__ __forceinline__ float eluf(float x) { return x > 0.f ? x : expm1f(x); }
__device__ __forceinline__ float lrelu(float x) { return x > 0.f ? x : 0.2f * x; }
__device__ __forceinline__ ushort f2bf(float f) {
  __hip_bfloat16 b = __float2bfloat16(f);
  return *(ushort*)&b;
}

// ---------------- W1 hi/lo split + transpose: Wt[n][k] ----------------
__global__ __launch_bounds__(256) void prep_w_kernel(const float* __restrict__ W1,
                                                     ushort* __restrict__ Wt_hi, ushort* __restrict__ Wt_lo) {
  int t = blockIdx.x * 256 + threadIdx.x;
  if (t >= DF * 64) return;
  int k = t >> 6, n = t & 63;
  float w = W1[t];
  ushort hi = f2bf(w);
  __hip_bfloat16 hb = *(__hip_bfloat16*)&hi;
  ushort lo = f2bf(w - __bfloat162float(hb));
  Wt_hi[(size_t)n * DF + k] = hi;
  Wt_lo[(size_t)n * DF + k] = lo;
}

// ---------------- layer-1 GEMM via MFMA (split bf16), fused scores + bf16 h1 ----------------
// C[M=NN, N=64] = x[NN,512] @ W1[512,64]; BM=128, BK=32, 4 waves.
#define AST 40   // padded LDS row stride (ushorts) for A tiles
#define BST 40
__global__ __launch_bounds__(256) void gemm1_mfma(const float* __restrict__ x,
                                                  const ushort* __restrict__ Wt_hi, const ushort* __restrict__ Wt_lo,
                                                  const float* __restrict__ a1s, const float* __restrict__ a1d,
                                                  ushort* __restrict__ h1b, float* __restrict__ s_src,
                                                  float* __restrict__ s_dst) {
  __shared__ __align__(16) char smem[33280];   // max(staging 30720, Cs 128*65*4=33280)
  ushort* As_hi = (ushort*)smem;               // [128][AST]
  ushort* As_lo = As_hi + 128 * AST;
  ushort* Bs_hi = As_lo + 128 * AST;           // [64][BST] (transposed: [n][k])
  ushort* Bs_lo = Bs_hi + 64 * BST;
  float* Cs = (float*)smem;                    // reused after last sync, stride 65

  const int tid = threadIdx.x;
  const int m0 = blockIdx.x * 128;
  const int wave = tid >> 6, l = tid & 63;
  const int wm = wave * 32;
  const int lm = l & 15, kg = (l >> 4) * 8;

  float4v acc[2][4];
#pragma unroll
  for (int i = 0; i < 2; ++i)
#pragma unroll
    for (int j = 0; j < 4; ++j) acc[i][j] = (float4v){0.f, 0.f, 0.f, 0.f};

  const int arow = tid >> 1;            // staging: 2 threads per row
  const int ac0 = (tid & 1) * 16;
  const int grow = m0 + arow;
  const int bn = tid & 63, bk = (tid >> 6) * 8;

  for (int k0 = 0; k0 < DF; k0 += 32) {
    // stage A (x) hi/lo
#pragma unroll
    for (int i = 0; i < 4; ++i) {
      float4 v = make_float4(0.f, 0.f, 0.f, 0.f);
      if (grow < NN) v = *(const float4*)&x[(size_t)grow * DF + k0 + ac0 + 4 * i];
      ushort4 h, lo;
      h.x = f2bf(v.x); h.y = f2bf(v.y); h.z = f2bf(v.z); h.w = f2bf(v.w);
      lo.x = f2bf(v.x - __bfloat162float(*(__hip_bfloat16*)&h.x));
      lo.y = f2bf(v.y - __bfloat162float(*(__hip_bfloat16*)&h.y));
      lo.z = f2bf(v.z - __bfloat162float(*(__hip_bfloat16*)&h.z));
      lo.w = f2bf(v.w - __bfloat162float(*(__hip_bfloat16*)&h.w));
      *(ushort4*)&As_hi[arow * AST + ac0 + 4 * i] = h;
      *(ushort4*)&As_lo[arow * AST + ac0 + 4 * i] = lo;
    }
    // stage B (Wt) hi/lo, already transposed [n][k]
    *(uint4*)&Bs_hi[bn * BST + bk] = *(const uint4*)&Wt_hi[(size_t)bn * DF + k0 + bk];
    *(uint4*)&Bs_lo[bn * BST + bk] = *(const uint4*)&Wt_lo[(size_t)bn * DF + k0 + bk];
    __syncthreads();

    short8v ah[2], al[2], bh[4], bl[4];
#pragma unroll
    for (int mt = 0; mt < 2; ++mt) {
      ah[mt] = *(const short8v*)&As_hi[(wm + mt * 16 + lm) * AST + kg];
      al[mt] = *(const short8v*)&As_lo[(wm + mt * 16 + lm) * AST + kg];
    }
#pragma unroll
    for (int nt = 0; nt < 4; ++nt) {
      bh[nt] = *(const short8v*)&Bs_hi[(nt * 16 + lm) * BST + kg];
      bl[nt] = *(const short8v*)&Bs_lo[(nt * 16 + lm) * BST + kg];
    }
#pragma unroll
    for (int mt = 0; mt < 2; ++mt)
#pragma unroll
      for (int nt = 0; nt < 4; ++nt) {
        acc[mt][nt] = __builtin_amdgcn_mfma_f32_16x16x32_bf16(ah[mt], bh[nt], acc[mt][nt], 0, 0, 0);
        acc[mt][nt] = __builtin_amdgcn_mfma_f32_16x16x32_bf16(ah[mt], bl[nt], acc[mt][nt], 0, 0, 0);
        acc[mt][nt] = __builtin_amdgcn_mfma_f32_16x16x32_bf16(al[mt], bh[nt], acc[mt][nt], 0, 0, 0);
      }
    __syncthreads();
  }

  // epilogue: acc -> Cs (f32, stride 65)
#pragma unroll
  for (int mt = 0; mt < 2; ++mt)
#pragma unroll
    for (int nt = 0; nt < 4; ++nt)
#pragma unroll
      for (int r = 0; r < 4; ++r)
        Cs[(wm + mt * 16 + (l >> 4) * 4 + r) * 65 + nt * 16 + lm] = acc[mt][nt][r];
  __syncthreads();

  // h1b bf16 write: thread t -> row t>>1, cols (t&1)*32..+32
  {
    int row = tid >> 1, c0 = (tid & 1) * 32;
    int g = m0 + row;
    if (g < NN) {
      uint u[16];
#pragma unroll
      for (int j = 0; j < 16; ++j) {
        uint p0 = f2bf(Cs[row * 65 + c0 + 2 * j]);
        uint p1 = f2bf(Cs[row * 65 + c0 + 2 * j + 1]);
        u[j] = p0 | (p1 << 16);
      }
#pragma unroll
      for (int q = 0; q < 4; ++q)
        *(uint4*)&h1b[(size_t)g * 64 + c0 + 8 * q] = *(uint4*)&u[4 * q];
      // scores: 4 heads per thread
      int half = tid & 1;
      float4 ssv, ddv;
      float* ssp = &ssv.x;
      float* ddp = &ddv.x;
#pragma unroll
      for (int hq = 0; hq < 4; ++hq) {
        int hh = half * 4 + hq;
        float ss = 0.f, dd = 0.f;
#pragma unroll
        for (int u8 = 0; u8 < 8; ++u8) {
          float hv = Cs[row * 65 + hh * 8 + u8];
          ss = fmaf(hv, a1s[hh * 8 + u8], ss);
          dd = fmaf(hv, a1d[hh * 8 + u8], dd);
        }
        ssp[hq] = ss; ddp[hq] = dd;
      }
      *(float4*)&s_src[(size_t)g * 8 + half * 4] = ssv;
      *(float4*)&s_dst[(size_t)g * 8 + half * 4] = ddv;
    }
  }
}

// ---------------- GEMM: C[M,N] = A[M,K] @ B[K,N] (f32 vector; used for layer 2) ----------------
template<bool ELU_A, bool WRITE_F32, bool WRITE_BF16>
__global__ __launch_bounds__(256) void gemm64(const float* __restrict__ A, const float* __restrict__ B,
                                              float* __restrict__ C, __hip_bfloat162* __restrict__ Cb,
                                              int M, int N, int K) {
  __shared__ float As[32][68];
  __shared__ float Bs[32][68];
  const int tid = threadIdx.x;
  const int m0 = blockIdx.x * 64;
  const int n0 = blockIdx.y * 64;
  const int tx = tid & 15, ty = tid >> 4;
  float acc[4][4] = {};
  for (int k0 = 0; k0 < K; k0 += 32) {
    for (int j = tid; j < 512; j += 256) {
      int r = j >> 3, kq = j & 7;
      int row = m0 + r;
      float4 v = make_float4(0.f, 0.f, 0.f, 0.f);
      if (row < M) v = *(const float4*)&A[(size_t)row * K + k0 + kq * 4];
      if (ELU_A) { v.x = eluf(v.x); v.y = eluf(v.y); v.z = eluf(v.z); v.w = eluf(v.w); }
      As[kq * 4 + 0][r] = v.x; As[kq * 4 + 1][r] = v.y;
      As[kq * 4 + 2][r] = v.z; As[kq * 4 + 3][r] = v.w;
    }
    for (int j = tid; j < 512; j += 256) {
      int kr = j >> 4, nq = j & 15;
      *(float4*)&Bs[kr][nq * 4] = *(const float4*)&B[(size_t)(k0 + kr) * N + n0 + nq * 4];
    }
    __syncthreads();
#pragma unroll
    for (int kk = 0; kk < 32; ++kk) {
      float4 a4 = *(const float4*)&As[kk][ty * 4];
      float4 b4 = *(const float4*)&Bs[kk][tx * 4];
      float av[4] = {a4.x, a4.y, a4.z, a4.w};
      float bv[4] = {b4.x, b4.y, b4.z, b4.w};
#pragma unroll
      for (int i = 0; i < 4; ++i)
#pragma unroll
        for (int jj = 0; jj < 4; ++jj)
          acc[i][jj] = fmaf(av[i], bv[jj], acc[i][jj]);
    }
    __syncthreads();
  }
#pragma unroll
  for (int i = 0; i < 4; ++i) {
    int row = m0 + ty * 4 + i;
    if (row < M) {
      if (WRITE_F32) {
        float4 v = make_float4(acc[i][0], acc[i][1], acc[i][2], acc[i][3]);
        *(float4*)&C[(size_t)row * N + n0 + tx * 4] = v;
      }
      if (WRITE_BF16) {
        __hip_bfloat162 p0, p1;
        p0.x = __float2bfloat16(acc[i][0]); p0.y = __float2bfloat16(acc[i][1]);
        p1.x = __float2bfloat16(acc[i][2]); p1.y = __float2bfloat16(acc[i][3]);
        size_t base = ((size_t)row * N + n0 + tx * 4) >> 1;
        Cb[base] = p0; Cb[base + 1] = p1;
      }
    }
  }
}

// ---------------- per-node attention scores (bf16 h, U=16) ----------------
__global__ __launch_bounds__(256) void s2_kernel(const __hip_bfloat162* __restrict__ h, const float* __restrict__ asrc,
                                                 const float* __restrict__ adst, float* __restrict__ s_src,
                                                 float* __restrict__ s_dst, int n) {
  int node = blockIdx.x * 256 + threadIdx.x;
  if (node >= n) return;
  const __hip_bfloat162* hp = h + (size_t)node * 64;
#pragma unroll
  for (int hh = 0; hh < 8; ++hh) {
    float ss = 0.f, dd = 0.f;
#pragma unroll
    for (int u2 = 0; u2 < 8; ++u2) {
      float2 f = __bfloat1622float2(hp[hh * 8 + u2]);
      float a0 = asrc[hh * 16 + u2 * 2], a1 = asrc[hh * 16 + u2 * 2 + 1];
      float b0 = adst[hh * 16 + u2 * 2], b1 = adst[hh * 16 + u2 * 2 + 1];
      ss += f.x * a0 + f.y * a1;
      dd += f.x * b0 + f.y * b1;
    }
    s_src[(size_t)node * 8 + hh] = ss;
    s_dst[(size_t)node * 8 + hh] = dd;
  }
}

// ---------------- CSR build via 512-bucket sort ----------------
__global__ __launch_bounds__(256) void bkt_hist_kernel(const int2* __restrict__ edges, int* __restrict__ bkt_cnt) {
  __shared__ int h[NBKT];
  const int tid = threadIdx.x;
  h[tid] = 0; h[tid + 256] = 0;
  __syncthreads();
  const int i0 = blockIdx.x * EDGES_PER_BKT_BLK;
  const int i1 = min(i0 + EDGES_PER_BKT_BLK, NE);
  for (int i = i0 + tid; i < i1; i += 256) atomicAdd(&h[edges[i].x / BKT_W], 1);
  __syncthreads();
  if (h[tid]) atomicAdd(&bkt_cnt[tid], h[tid]);
  if (h[tid + 256]) atomicAdd(&bkt_cnt[tid + 256], h[tid + 256]);
}

__global__ __launch_bounds__(NBKT) void bkt_scan_kernel(const int* __restrict__ bkt_cnt, int* __restrict__ bkt_base,
                                                        int* __restrict__ bkt_cursor, int* __restrict__ row_off) {
  __shared__ int s[NBKT];
  int tid = threadIdx.x;
  int v = bkt_cnt[tid];
  s[tid] = v;
  __syncthreads();
  for (int off = 1; off < NBKT; off <<= 1) {
    int t = (tid >= off) ? s[tid - off] : 0;
    __syncthreads();
    s[tid] += t;
    __syncthreads();
  }
  int excl = s[tid] - v;
  bkt_base[tid] = excl;
  bkt_cursor[tid] = excl;
  if (tid == NBKT - 1) bkt_base[NBKT] = s[tid];
  if (tid == 0) row_off[NN] = NE;
}

__global__ __launch_bounds__(256) void bkt_reorder_kernel(const int2* __restrict__ edges, int* __restrict__ bkt_cursor,
                                                          int2* __restrict__ pairs) {
  __shared__ int h[NBKT];
  __shared__ int lbase[NBKT];
  __shared__ int cur[NBKT];
  const int tid = threadIdx.x;
  h[tid] = 0; h[tid + 256] = 0;
  __syncthreads();
  const int i0 = blockIdx.x * EDGES_PER_BKT_BLK;
  const int i1 = min(i0 + EDGES_PER_BKT_BLK, NE);
  for (int i = i0 + tid; i < i1; i += 256) atomicAdd(&h[edges[i].x / BKT_W], 1);
  __syncthreads();
#pragma unroll
  for (int q = 0; q < 2; ++q) {
    int b = tid + q * 256;
    int c = h[b];
    lbase[b] = c ? atomicAdd(&bkt_cursor[b], c) : 0;
    cur[b] = 0;
  }
  __syncthreads();
  for (int i = i0 + tid; i < i1; i += 256) {
    int2 e = edges[i];
    int bk = e.x / BKT_W;
    int r = atomicAdd(&cur[bk], 1);
    pairs[lbase[bk] + r] = e;
  }
}

__global__ __launch_bounds__(256) void bkt_build_kernel(const int2* __restrict__ pairs, const int* __restrict__ bkt_base,
                                                        int* __restrict__ row_off, int* __restrict__ ssrc) {
  __shared__ int hist[256];
  __shared__ int ts[256];
  __shared__ int cur[256];
  const int b = blockIdx.x, tid = threadIdx.x;
  const int d0 = b * BKT_W;
  if (d0 >= NN) return;
  const int nd = min(BKT_W, NN - d0);
  const int beg = bkt_base[b], end = bkt_base[b + 1];
  hist[tid] = 0;
  __syncthreads();
  for (int i = beg + tid; i < end; i += 256) atomicAdd(&hist[pairs[i].x - d0], 1);
  __syncthreads();
  int v = hist[tid];
  ts[tid] = v;
  __syncthreads();
  for (int off = 1; off < 256; off <<= 1) {
    int t = (tid >= off) ? ts[tid - off] : 0;
    __syncthreads();
    ts[tid] += t;
    __syncthreads();
  }
  int excl = ts[tid] - v;
  if (tid < nd) row_off[d0 + tid] = beg + excl;
  cur[tid] = beg + excl;
  __syncthreads();
  for (int i = beg + tid; i < end; i += 256) {
    int2 e = pairs[i];
    int pos = atomicAdd(&cur[e.x - d0], 1);
    ssrc[pos] = e.y;
  }
}

// ---------------- layer-1 aggregation: wave per node, 4-edge unroll, bf16 values ----------------
__global__ __launch_bounds__(256) void agg1_kernel(const int* __restrict__ row_off, const int* __restrict__ srcs,
                                                   const float* __restrict__ s_src, const float* __restrict__ s_dst,
                                                   const __hip_bfloat16* __restrict__ hb, float* __restrict__ out, int n) {
  int wave = (blockIdx.x * 256 + threadIdx.x) >> 6;
  int lane = threadIdx.x & 63;
  if (wave >= n) return;
  int hh = lane >> 3;
  float sd = s_dst[(size_t)wave * 8 + hh];
  int beg = row_off[wave], end = row_off[wave + 1];
  float acc = 0.f, den = 0.f;
  int i = beg;
  for (; i + 4 <= end; i += 4) {
    int s0 = srcs[i], s1 = srcs[i + 1], s2 = srcs[i + 2], s3 = srcs[i + 3];
    float e0 = s_src[(size_t)s0 * 8 + hh];
    float e1 = s_src[(size_t)s1 * 8 + hh];
    float e2 = s_src[(size_t)s2 * 8 + hh];
    float e3 = s_src[(size_t)s3 * 8 + hh];
    float h0 = __bfloat162float(hb[(size_t)s0 * 64 + lane]);
    float h1 = __bfloat162float(hb[(size_t)s1 * 64 + lane]);
    float h2 = __bfloat162float(hb[(size_t)s2 * 64 + lane]);
    float h3 = __bfloat162float(hb[(size_t)s3 * 64 + lane]);
    float x0 = __expf(lrelu(sd + e0));
    float x1 = __expf(lrelu(sd + e1));
    float x2 = __expf(lrelu(sd + e2));
    float x3 = __expf(lrelu(sd + e3));
    den += (x0 + x1) + (x2 + x3);
    acc = fmaf(x0, h0, fmaf(x1, h1, fmaf(x2, h2, fmaf(x3, h3, acc))));
  }
  for (; i < end; ++i) {
    int s0 = srcs[i];
    float x0 = __expf(lrelu(sd + s_src[(size_t)s0 * 8 + hh]));
    den += x0;
    acc = fmaf(x0, __bfloat162float(hb[(size_t)s0 * 64 + lane]), acc);
  }
  out[(size_t)wave * 64 + lane] = acc / fmaxf(den, 1e-9f);
}

// ---------------- layer-2 aggregation + head average, bf16 values ----------------
__global__ __launch_bounds__(256) void agg2_kernel(const int* __restrict__ row_off, const int* __restrict__ srcs,
                                                   const float* __restrict__ s_src, const float* __restrict__ s_dst,
                                                   const __hip_bfloat162* __restrict__ h2b, float* __restrict__ out, int n) {
  int wave = (blockIdx.x * 256 + threadIdx.x) >> 6;
  int lane = threadIdx.x & 63;
  if (wave >= n) return;
  int hh = lane >> 3, o2 = lane & 7;
  float sd = s_dst[(size_t)wave * 8 + hh];
  int beg = row_off[wave], end = row_off[wave + 1];
  float a0 = 0.f, a1 = 0.f, den = 0.f;
  int i = beg;
  for (; i + 4 <= end; i += 4) {
    int s0 = srcs[i], s1 = srcs[i + 1], s2 = srcs[i + 2], s3 = srcs[i + 3];
    float e0 = s_src[(size_t)s0 * 8 + hh];
    float e1 = s_src[(size_t)s1 * 8 + hh];
    float e2 = s_src[(size_t)s2 * 8 + hh];
    float e3 = s_src[(size_t)s3 * 8 + hh];
    float2 v0 = __bfloat1622float2(h2b[(size_t)s0 * 64 + hh * 8 + o2]);
    float2 v1 = __bfloat1622float2(h2b[(size_t)s1 * 64 + hh * 8 + o2]);
    float2 v2 = __bfloat1622float2(h2b[(size_t)s2 * 64 + hh * 8 + o2]);
    float2 v3 = __bfloat1622float2(h2b[(size_t)s3 * 64 + hh * 8 + o2]);
    float x0 = __expf(lrelu(sd + e0));
    float x1 = __expf(lrelu(sd + e1));
    float x2 = __expf(lrelu(sd + e2));
    float x3 = __expf(lrelu(sd + e3));
    den += (x0 + x1) + (x2 + x3);
    a0 = fmaf(x0, v0.x, fmaf(x1, v1.x, fmaf(x2, v2.x, fmaf(x3, v3.x, a0))));
    a1 = fmaf(x0, v0.y, fmaf(x1, v1.y, fmaf(x2, v2.y, fmaf(x3, v3.y, a1))));
  }
  for (; i < end; ++i) {
    int s0 = srcs[i];
    float x0 = __expf(lrelu(sd + s_src[(size_t)s0 * 8 + hh]));
    float2 v0 = __bfloat1622float2(h2b[(size_t)s0 * 64 + hh * 8 + o2]);
    den += x0;
    a0 = fmaf(x0, v0.x, a0);
    a1 = fmaf(x0, v0.y, a1);
  }
  float r0 = a0 / fmaxf(den, 1e-9f);
  float r1 = a1 / fmaxf(den, 1e-9f);
  for (int m = 8; m < 64; m <<= 1) {
    r0 += __shfl_xor(r0, m, 64);
    r1 += __shfl_xor(r1, m, 64);
  }
  if (lane < 8) {
    float2 w = make_float2(r0 * 0.125f, r1 * 0.125f);
    *(float2*)&out[(size_t)wave * 16 + lane * 2] = w;
  }
}

// ---------------- final index gather ----------------
__global__ void gather_kernel(const float* __restrict__ out2, const int* __restrict__ idx,
                              float* __restrict__ out, int ni) {
  int t = blockIdx.x * blockDim.x + threadIdx.x;
  if (t < ni * 4) {
    int i = t >> 2, q = t & 3;
    int node = idx[i];
    *(float4*)&out[(size_t)i * 16 + q * 4] = *(const float4*)&out2[(size_t)node * 16 + q * 4];
  }
}

extern "C" void kernel_launch(void* const* d_in, const int* in_sizes, int n_in,
                              void* d_out, int out_size, void* d_ws, size_t ws_size,
                              hipStream_t stream) {
  const float* x   = (const float*)d_in[0];
  const int2* edges = (const int2*)d_in[1];
  const int* indices = (const int*)d_in[2];
  const float* W1  = (const float*)d_in[3];
  const float* a1s = (const float*)d_in[4];
  const float* a1d = (const float*)d_in[5];
  const float* W2  = (const float*)d_in[6];
  const float* a2s = (const float*)d_in[7];
  const float* a2d = (const float*)d_in[8];
  float* out = (float*)d_out;

  char* ws = (char*)d_ws;
  size_t off = 0;
  auto alloc = [&](size_t bytes) {
    void* p = ws + off;
    off = (off + bytes + 255) & ~(size_t)255;
    return p;
  };
  float* s1src = (float*)alloc((size_t)NN * 8 * 4);
  float* s1dst = (float*)alloc((size_t)NN * 8 * 4);
  float* out1  = (float*)alloc((size_t)NN * 64 * 4);
  float* out2  = (float*)alloc((size_t)NN * 16 * 4);
  ushort* h1b  = (ushort*)alloc((size_t)NN * 64 * 2);
  __hip_bfloat162* h2b = (__hip_bfloat162*)alloc((size_t)NN * 128 * 2);
  int* row_off = (int*)alloc(((size_t)NN + 1) * 4);
  int* ssrc    = (int*)alloc((size_t)NE * 4);
  int2* pairs  = (int2*)alloc((size_t)NE * 8);
  ushort* Wt_hi = (ushort*)alloc((size_t)DF * 64 * 2);
  ushort* Wt_lo = (ushort*)alloc((size_t)DF * 64 * 2);
  int* bkt_cnt    = (int*)alloc(NBKT * 4);
  int* bkt_base   = (int*)alloc((NBKT + 1) * 4);
  int* bkt_cursor = (int*)alloc(NBKT * 4);

  hipMemsetAsync(bkt_cnt, 0, NBKT * 4, stream);

  dim3 b256(256);
  // W1 split/transpose, then layer-1 GEMM (MFMA, fused scores + bf16 h1)
  prep_w_kernel<<<dim3((DF * 64 + 255) / 256), b256, 0, stream>>>(W1, Wt_hi, Wt_lo);
  gemm1_mfma<<<dim3((NN + 127) / 128), b256, 0, stream>>>(x, Wt_hi, Wt_lo, a1s, a1d, h1b, s1src, s1dst);
  // CSR build via bucket sort
  bkt_hist_kernel<<<dim3(NBKT), b256, 0, stream>>>(edges, bkt_cnt);
  bkt_scan_kernel<<<dim3(1), dim3(NBKT), 0, stream>>>(bkt_cnt, bkt_base, bkt_cursor, row_off);
  bkt_reorder_kernel<<<dim3(NBKT), b256, 0, stream>>>(edges, bkt_cursor, pairs);
  bkt_build_kernel<<<dim3(NBKT), b256, 0, stream>>>(pairs, bkt_base, row_off, ssrc);
  // layer 1 aggregation (bf16 value gather)
  agg1_kernel<<<dim3(NN / 4), b256, 0, stream>>>(row_off, ssrc, s1src, s1dst, (const __hip_bfloat16*)h1b, out1, NN);
  // layer 2 GEMM with fused ELU: h2b (bf16) = elu(out1) @ W2
  gemm64<true, false, true><<<dim3((NN + 63) / 64, 2), b256, 0, stream>>>(out1, W2, nullptr, h2b, NN, 128, 64);
  // layer 2 scores
  s2_kernel<<<dim3((NN + 255) / 256), b256, 0, stream>>>(h2b, a2s, a2d, s1src, s1dst, NN);
  // layer 2 aggregation + head average
  agg2_kernel<<<dim3(NN / 4), b256, 0, stream>>>(row_off, ssrc, s1src, s1dst, h2b, out2, NN);
  // final gather
  gather_kernel<<<dim3((NIDX * 4 + 255) / 256), b256, 0, stream>>>(out2, indices, out, NIDX);
}

// Round 6
// 263.671 us; speedup vs baseline: 3.4608x; 1.3049x over previous
//
#include <hip/hip_runtime.h>
#include <hip/hip_bf16.h>

#define NN 100000
#define NE 1600000
#define DF 512
#define NIDX 10000

#define NBKT 512
#define BKT_W 196                 // ceil(100000/512); 512*196 = 100352 >= NN
#define EDGES_PER_BKT_BLK 3125    // NE / 512 exactly

typedef __attribute__((ext_vector_type(8))) short short8v;
typedef __attribute__((ext_vector_type(4))) float float4v;

__device__ __forceinline__ float eluf(float x) { return x > 0.f ? x : expm1f(x); }
__device__ __forceinline__ float lrelu(float x) { return x > 0.f ? x : 0.2f * x; }
__device__ __forceinline__ ushort f2bf(float f) {
  __hip_bfloat16 b = __float2bfloat16(f);
  return *(ushort*)&b;
}

// ---------------- W1 hi/lo split + transpose: Wt[n][k]; also zeroes bkt_cnt ----------------
__global__ __launch_bounds__(256) void prep_w_kernel(const float* __restrict__ W1,
                                                     ushort* __restrict__ Wt_hi, ushort* __restrict__ Wt_lo,
                                                     int* __restrict__ bkt_cnt) {
  if (blockIdx.x == 0) {
    bkt_cnt[threadIdx.x] = 0;
    bkt_cnt[threadIdx.x + 256] = 0;
  }
  int t = blockIdx.x * 256 + threadIdx.x;
  if (t >= DF * 64) return;
  int k = t >> 6, n = t & 63;
  float w = W1[t];
  ushort hi = f2bf(w);
  __hip_bfloat16 hb = *(__hip_bfloat16*)&hi;
  ushort lo = f2bf(w - __bfloat162float(hb));
  Wt_hi[(size_t)n * DF + k] = hi;
  Wt_lo[(size_t)n * DF + k] = lo;
}

// ---------------- layer-1 GEMM via MFMA (split bf16), fused scores + bf16 h1 ----------------
#define AST 40
#define BST 40
__global__ __launch_bounds__(256) void gemm1_mfma(const float* __restrict__ x,
                                                  const ushort* __restrict__ Wt_hi, const ushort* __restrict__ Wt_lo,
                                                  const float* __restrict__ a1s, const float* __restrict__ a1d,
                                                  ushort* __restrict__ h1b, float* __restrict__ s_src,
                                                  float* __restrict__ s_dst) {
  __shared__ __align__(16) char smem[33280];
  ushort* As_hi = (ushort*)smem;               // [128][AST]
  ushort* As_lo = As_hi + 128 * AST;
  ushort* Bs_hi = As_lo + 128 * AST;           // [64][BST]
  ushort* Bs_lo = Bs_hi + 64 * BST;
  float* Cs = (float*)smem;                    // reused after last sync, stride 65

  const int tid = threadIdx.x;
  const int m0 = blockIdx.x * 128;
  const int wave = tid >> 6, l = tid & 63;
  const int wm = wave * 32;
  const int lm = l & 15, kg = (l >> 4) * 8;

  float4v acc[2][4];
#pragma unroll
  for (int i = 0; i < 2; ++i)
#pragma unroll
    for (int j = 0; j < 4; ++j) acc[i][j] = (float4v){0.f, 0.f, 0.f, 0.f};

  const int arow = tid >> 1;
  const int ac0 = (tid & 1) * 16;
  const int grow = m0 + arow;
  const int bn = tid & 63, bk = (tid >> 6) * 8;

  for (int k0 = 0; k0 < DF; k0 += 32) {
#pragma unroll
    for (int i = 0; i < 4; ++i) {
      float4 v = make_float4(0.f, 0.f, 0.f, 0.f);
      if (grow < NN) v = *(const float4*)&x[(size_t)grow * DF + k0 + ac0 + 4 * i];
      ushort4 h, lo;
      h.x = f2bf(v.x); h.y = f2bf(v.y); h.z = f2bf(v.z); h.w = f2bf(v.w);
      lo.x = f2bf(v.x - __bfloat162float(*(__hip_bfloat16*)&h.x));
      lo.y = f2bf(v.y - __bfloat162float(*(__hip_bfloat16*)&h.y));
      lo.z = f2bf(v.z - __bfloat162float(*(__hip_bfloat16*)&h.z));
      lo.w = f2bf(v.w - __bfloat162float(*(__hip_bfloat16*)&h.w));
      *(ushort4*)&As_hi[arow * AST + ac0 + 4 * i] = h;
      *(ushort4*)&As_lo[arow * AST + ac0 + 4 * i] = lo;
    }
    *(uint4*)&Bs_hi[bn * BST + bk] = *(const uint4*)&Wt_hi[(size_t)bn * DF + k0 + bk];
    *(uint4*)&Bs_lo[bn * BST + bk] = *(const uint4*)&Wt_lo[(size_t)bn * DF + k0 + bk];
    __syncthreads();

    short8v ah[2], al[2], bh[4], bl[4];
#pragma unroll
    for (int mt = 0; mt < 2; ++mt) {
      ah[mt] = *(const short8v*)&As_hi[(wm + mt * 16 + lm) * AST + kg];
      al[mt] = *(const short8v*)&As_lo[(wm + mt * 16 + lm) * AST + kg];
    }
#pragma unroll
    for (int nt = 0; nt < 4; ++nt) {
      bh[nt] = *(const short8v*)&Bs_hi[(nt * 16 + lm) * BST + kg];
      bl[nt] = *(const short8v*)&Bs_lo[(nt * 16 + lm) * BST + kg];
    }
#pragma unroll
    for (int mt = 0; mt < 2; ++mt)
#pragma unroll
      for (int nt = 0; nt < 4; ++nt) {
        acc[mt][nt] = __builtin_amdgcn_mfma_f32_16x16x32_bf16(ah[mt], bh[nt], acc[mt][nt], 0, 0, 0);
        acc[mt][nt] = __builtin_amdgcn_mfma_f32_16x16x32_bf16(ah[mt], bl[nt], acc[mt][nt], 0, 0, 0);
        acc[mt][nt] = __builtin_amdgcn_mfma_f32_16x16x32_bf16(al[mt], bh[nt], acc[mt][nt], 0, 0, 0);
      }
    __syncthreads();
  }

#pragma unroll
  for (int mt = 0; mt < 2; ++mt)
#pragma unroll
    for (int nt = 0; nt < 4; ++nt)
#pragma unroll
      for (int r = 0; r < 4; ++r)
        Cs[(wm + mt * 16 + (l >> 4) * 4 + r) * 65 + nt * 16 + lm] = acc[mt][nt][r];
  __syncthreads();

  {
    int row = tid >> 1, c0 = (tid & 1) * 32;
    int g = m0 + row;
    if (g < NN) {
      uint u[16];
#pragma unroll
      for (int j = 0; j < 16; ++j) {
        uint p0 = f2bf(Cs[row * 65 + c0 + 2 * j]);
        uint p1 = f2bf(Cs[row * 65 + c0 + 2 * j + 1]);
        u[j] = p0 | (p1 << 16);
      }
#pragma unroll
      for (int q = 0; q < 4; ++q)
        *(uint4*)&h1b[(size_t)g * 64 + c0 + 8 * q] = *(uint4*)&u[4 * q];
      int half = tid & 1;
      float4 ssv, ddv;
      float* ssp = &ssv.x;
      float* ddp = &ddv.x;
#pragma unroll
      for (int hq = 0; hq < 4; ++hq) {
        int hh = half * 4 + hq;
        float ss = 0.f, dd = 0.f;
#pragma unroll
        for (int u8 = 0; u8 < 8; ++u8) {
          float hv = Cs[row * 65 + hh * 8 + u8];
          ss = fmaf(hv, a1s[hh * 8 + u8], ss);
          dd = fmaf(hv, a1d[hh * 8 + u8], dd);
        }
        ssp[hq] = ss; ddp[hq] = dd;
      }
      *(float4*)&s_src[(size_t)g * 8 + half * 4] = ssv;
      *(float4*)&s_dst[(size_t)g * 8 + half * 4] = ddv;
    }
  }
}

// ---------------- layer-2 GEMM (f32 vector) + fused bf16 write + fused scores ----------------
// N=128, grid.y in {0,1}; block handles cols n0..n0+63 = heads (n0>>4)..(n0>>4)+3 fully.
__global__ __launch_bounds__(256) void gemm2_fused(const float* __restrict__ A, const float* __restrict__ B,
                                                   __hip_bfloat162* __restrict__ Cb,
                                                   const float* __restrict__ a2s, const float* __restrict__ a2d,
                                                   float* __restrict__ s_src, float* __restrict__ s_dst,
                                                   int M, int N, int K) {
  __shared__ float sm[2 * 32 * 68];            // As | Bs; reused as Cs (64*65 <= 4352)
  float* As = sm;                              // [32][68]
  float* Bs = sm + 32 * 68;
  float* Cs = sm;                              // stride 65
  const int tid = threadIdx.x;
  const int m0 = blockIdx.x * 64;
  const int n0 = blockIdx.y * 64;
  const int tx = tid & 15, ty = tid >> 4;
  float acc[4][4] = {};
  for (int k0 = 0; k0 < K; k0 += 32) {
    for (int j = tid; j < 512; j += 256) {
      int r = j >> 3, kq = j & 7;
      int row = m0 + r;
      float4 v = make_float4(0.f, 0.f, 0.f, 0.f);
      if (row < M) v = *(const float4*)&A[(size_t)row * K + k0 + kq * 4];
      v.x = eluf(v.x); v.y = eluf(v.y); v.z = eluf(v.z); v.w = eluf(v.w);
      As[(kq * 4 + 0) * 68 + r] = v.x; As[(kq * 4 + 1) * 68 + r] = v.y;
      As[(kq * 4 + 2) * 68 + r] = v.z; As[(kq * 4 + 3) * 68 + r] = v.w;
    }
    for (int j = tid; j < 512; j += 256) {
      int kr = j >> 4, nq = j & 15;
      *(float4*)&Bs[kr * 68 + nq * 4] = *(const float4*)&B[(size_t)(k0 + kr) * N + n0 + nq * 4];
    }
    __syncthreads();
#pragma unroll
    for (int kk = 0; kk < 32; ++kk) {
      float4 a4 = *(const float4*)&As[kk * 68 + ty * 4];
      float4 b4 = *(const float4*)&Bs[kk * 68 + tx * 4];
      float av[4] = {a4.x, a4.y, a4.z, a4.w};
      float bv[4] = {b4.x, b4.y, b4.z, b4.w};
#pragma unroll
      for (int i = 0; i < 4; ++i)
#pragma unroll
        for (int jj = 0; jj < 4; ++jj)
          acc[i][jj] = fmaf(av[i], bv[jj], acc[i][jj]);
    }
    __syncthreads();
  }
  // bf16 write + stash acc into LDS for score computation
#pragma unroll
  for (int i = 0; i < 4; ++i) {
    int row = m0 + ty * 4 + i;
    if (row < M) {
      __hip_bfloat162 p0, p1;
      p0.x = __float2bfloat16(acc[i][0]); p0.y = __float2bfloat16(acc[i][1]);
      p1.x = __float2bfloat16(acc[i][2]); p1.y = __float2bfloat16(acc[i][3]);
      size_t base = ((size_t)row * N + n0 + tx * 4) >> 1;
      Cb[base] = p0; Cb[base + 1] = p1;
    }
#pragma unroll
    for (int jj = 0; jj < 4; ++jj)
      Cs[(ty * 4 + i) * 65 + tx * 4 + jj] = acc[i][jj];
  }
  __syncthreads();
  // scores: 64 rows x 4 heads (this block's half)
  {
    int row = tid >> 2, q = tid & 3;
    int g = m0 + row;
    if (g < M) {
      int hh = (n0 >> 4) + q;
      float ss = 0.f, dd = 0.f;
#pragma unroll
      for (int u = 0; u < 16; ++u) {
        float v = Cs[row * 65 + q * 16 + u];
        ss = fmaf(v, a2s[hh * 16 + u], ss);
        dd = fmaf(v, a2d[hh * 16 + u], dd);
      }
      s_src[(size_t)g * 8 + hh] = ss;
      s_dst[(size_t)g * 8 + hh] = dd;
    }
  }
}

// ---------------- CSR build via 512-bucket sort (packed pairs) ----------------
__global__ __launch_bounds__(256) void bkt_hist_kernel(const int2* __restrict__ edges, int* __restrict__ bkt_cnt) {
  __shared__ int h[NBKT];
  const int tid = threadIdx.x;
  h[tid] = 0; h[tid + 256] = 0;
  __syncthreads();
  const int i0 = blockIdx.x * EDGES_PER_BKT_BLK;
  const int i1 = min(i0 + EDGES_PER_BKT_BLK, NE);
  for (int i = i0 + tid; i < i1; i += 256) atomicAdd(&h[edges[i].x / BKT_W], 1);
  __syncthreads();
  if (h[tid]) atomicAdd(&bkt_cnt[tid], h[tid]);
  if (h[tid + 256]) atomicAdd(&bkt_cnt[tid + 256], h[tid + 256]);
}

__global__ __launch_bounds__(NBKT) void bkt_scan_kernel(const int* __restrict__ bkt_cnt, int* __restrict__ bkt_base,
                                                        int* __restrict__ bkt_cursor, int* __restrict__ row_off) {
  __shared__ int s[NBKT];
  int tid = threadIdx.x;
  int v = bkt_cnt[tid];
  s[tid] = v;
  __syncthreads();
  for (int off = 1; off < NBKT; off <<= 1) {
    int t = (tid >= off) ? s[tid - off] : 0;
    __syncthreads();
    s[tid] += t;
    __syncthreads();
  }
  int excl = s[tid] - v;
  bkt_base[tid] = excl;
  bkt_cursor[tid] = excl;
  if (tid == NBKT - 1) bkt_base[NBKT] = s[tid];
  if (tid == 0) row_off[NN] = NE;
}

__global__ __launch_bounds__(256) void bkt_reorder_kernel(const int2* __restrict__ edges, int* __restrict__ bkt_cursor,
                                                          uint* __restrict__ pairs) {
  __shared__ int h[NBKT];
  __shared__ int lbase[NBKT];
  __shared__ int cur[NBKT];
  const int tid = threadIdx.x;
  h[tid] = 0; h[tid + 256] = 0;
  __syncthreads();
  const int i0 = blockIdx.x * EDGES_PER_BKT_BLK;
  const int i1 = min(i0 + EDGES_PER_BKT_BLK, NE);
  for (int i = i0 + tid; i < i1; i += 256) atomicAdd(&h[edges[i].x / BKT_W], 1);
  __syncthreads();
#pragma unroll
  for (int q = 0; q < 2; ++q) {
    int b = tid + q * 256;
    int c = h[b];
    lbase[b] = c ? atomicAdd(&bkt_cursor[b], c) : 0;
    cur[b] = 0;
  }
  __syncthreads();
  for (int i = i0 + tid; i < i1; i += 256) {
    int2 e = edges[i];
    int bk = e.x / BKT_W;
    int r = atomicAdd(&cur[bk], 1);
    pairs[lbase[bk] + r] = ((uint)(e.x - bk * BKT_W) << 24) | (uint)e.y;
  }
}

__global__ __launch_bounds__(256) void bkt_build_kernel(const uint* __restrict__ pairs, const int* __restrict__ bkt_base,
                                                        int* __restrict__ row_off, int* __restrict__ ssrc) {
  __shared__ int hist[256];
  __shared__ int ts[256];
  __shared__ int cur[256];
  const int b = blockIdx.x, tid = threadIdx.x;
  const int d0 = b * BKT_W;
  if (d0 >= NN) return;
  const int nd = min(BKT_W, NN - d0);
  const int beg = bkt_base[b], end = bkt_base[b + 1];
  hist[tid] = 0;
  __syncthreads();
  for (int i = beg + tid; i < end; i += 256) atomicAdd(&hist[pairs[i] >> 24], 1);
  __syncthreads();
  int v = hist[tid];
  ts[tid] = v;
  __syncthreads();
  for (int off = 1; off < 256; off <<= 1) {
    int t = (tid >= off) ? ts[tid - off] : 0;
    __syncthreads();
    ts[tid] += t;
    __syncthreads();
  }
  int excl = ts[tid] - v;
  if (tid < nd) row_off[d0 + tid] = beg + excl;
  cur[tid] = beg + excl;
  __syncthreads();
  for (int i = beg + tid; i < end; i += 256) {
    uint p = pairs[i];
    int pos = atomicAdd(&cur[p >> 24], 1);
    ssrc[pos] = (int)(p & 0xFFFFFFu);
  }
}

// ---------------- layer-1 aggregation: wave per node, 4-edge unroll, bf16 values ----------------
__global__ __launch_bounds__(256) void agg1_kernel(const int* __restrict__ row_off, const int* __restrict__ srcs,
                                                   const float* __restrict__ s_src, const float* __restrict__ s_dst,
                                                   const __hip_bfloat16* __restrict__ hb, float* __restrict__ out, int n) {
  int wave = (blockIdx.x * 256 + threadIdx.x) >> 6;
  int lane = threadIdx.x & 63;
  if (wave >= n) return;
  int hh = lane >> 3;
  float sd = s_dst[(size_t)wave * 8 + hh];
  int beg = row_off[wave], end = row_off[wave + 1];
  float acc = 0.f, den = 0.f;
  int i = beg;
  for (; i + 4 <= end; i += 4) {
    int s0 = srcs[i], s1 = srcs[i + 1], s2 = srcs[i + 2], s3 = srcs[i + 3];
    float e0 = s_src[(size_t)s0 * 8 + hh];
    float e1 = s_src[(size_t)s1 * 8 + hh];
    float e2 = s_src[(size_t)s2 * 8 + hh];
    float e3 = s_src[(size_t)s3 * 8 + hh];
    float h0 = __bfloat162float(hb[(size_t)s0 * 64 + lane]);
    float h1 = __bfloat162float(hb[(size_t)s1 * 64 + lane]);
    float h2 = __bfloat162float(hb[(size_t)s2 * 64 + lane]);
    float h3 = __bfloat162float(hb[(size_t)s3 * 64 + lane]);
    float x0 = __expf(lrelu(sd + e0));
    float x1 = __expf(lrelu(sd + e1));
    float x2 = __expf(lrelu(sd + e2));
    float x3 = __expf(lrelu(sd + e3));
    den += (x0 + x1) + (x2 + x3);
    acc = fmaf(x0, h0, fmaf(x1, h1, fmaf(x2, h2, fmaf(x3, h3, acc))));
  }
  for (; i < end; ++i) {
    int s0 = srcs[i];
    float x0 = __expf(lrelu(sd + s_src[(size_t)s0 * 8 + hh]));
    den += x0;
    acc = fmaf(x0, __bfloat162float(hb[(size_t)s0 * 64 + lane]), acc);
  }
  out[(size_t)wave * 64 + lane] = acc / fmaxf(den, 1e-9f);
}

// ---------------- layer-2 aggregation over INDICES only + head average ----------------
__global__ __launch_bounds__(256) void agg2_idx_kernel(const int* __restrict__ row_off, const int* __restrict__ srcs,
                                                       const float* __restrict__ s_src, const float* __restrict__ s_dst,
                                                       const __hip_bfloat162* __restrict__ h2b, const int* __restrict__ idx,
                                                       float* __restrict__ out, int ni) {
  int w = (blockIdx.x * 256 + threadIdx.x) >> 6;
  int lane = threadIdx.x & 63;
  if (w >= ni) return;
  int node = idx[w];
  int hh = lane >> 3, o2 = lane & 7;
  float sd = s_dst[(size_t)node * 8 + hh];
  int beg = row_off[node], end = row_off[node + 1];
  float a0 = 0.f, a1 = 0.f, den = 0.f;
  int i = beg;
  for (; i + 4 <= end; i += 4) {
    int s0 = srcs[i], s1 = srcs[i + 1], s2 = srcs[i + 2], s3 = srcs[i + 3];
    float e0 = s_src[(size_t)s0 * 8 + hh];
    float e1 = s_src[(size_t)s1 * 8 + hh];
    float e2 = s_src[(size_t)s2 * 8 + hh];
    float e3 = s_src[(size_t)s3 * 8 + hh];
    float2 v0 = __bfloat1622float2(h2b[(size_t)s0 * 64 + hh * 8 + o2]);
    float2 v1 = __bfloat1622float2(h2b[(size_t)s1 * 64 + hh * 8 + o2]);
    float2 v2 = __bfloat1622float2(h2b[(size_t)s2 * 64 + hh * 8 + o2]);
    float2 v3 = __bfloat1622float2(h2b[(size_t)s3 * 64 + hh * 8 + o2]);
    float x0 = __expf(lrelu(sd + e0));
    float x1 = __expf(lrelu(sd + e1));
    float x2 = __expf(lrelu(sd + e2));
    float x3 = __expf(lrelu(sd + e3));
    den += (x0 + x1) + (x2 + x3);
    a0 = fmaf(x0, v0.x, fmaf(x1, v1.x, fmaf(x2, v2.x, fmaf(x3, v3.x, a0))));
    a1 = fmaf(x0, v0.y, fmaf(x1, v1.y, fmaf(x2, v2.y, fmaf(x3, v3.y, a1))));
  }
  for (; i < end; ++i) {
    int s0 = srcs[i];
    float x0 = __expf(lrelu(sd + s_src[(size_t)s0 * 8 + hh]));
    float2 v0 = __bfloat1622float2(h2b[(size_t)s0 * 64 + hh * 8 + o2]);
    den += x0;
    a0 = fmaf(x0, v0.x, a0);
    a1 = fmaf(x0, v0.y, a1);
  }
  float r0 = a0 / fmaxf(den, 1e-9f);
  float r1 = a1 / fmaxf(den, 1e-9f);
  for (int m = 8; m < 64; m <<= 1) {
    r0 += __shfl_xor(r0, m, 64);
    r1 += __shfl_xor(r1, m, 64);
  }
  if (lane < 8) {
    float2 wv = make_float2(r0 * 0.125f, r1 * 0.125f);
    *(float2*)&out[(size_t)w * 16 + lane * 2] = wv;
  }
}

extern "C" void kernel_launch(void* const* d_in, const int* in_sizes, int n_in,
                              void* d_out, int out_size, void* d_ws, size_t ws_size,
                              hipStream_t stream) {
  const float* x   = (const float*)d_in[0];
  const int2* edges = (const int2*)d_in[1];
  const int* indices = (const int*)d_in[2];
  const float* W1  = (const float*)d_in[3];
  const float* a1s = (const float*)d_in[4];
  const float* a1d = (const float*)d_in[5];
  const float* W2  = (const float*)d_in[6];
  const float* a2s = (const float*)d_in[7];
  const float* a2d = (const float*)d_in[8];
  float* out = (float*)d_out;

  char* ws = (char*)d_ws;
  size_t off = 0;
  auto alloc = [&](size_t bytes) {
    void* p = ws + off;
    off = (off + bytes + 255) & ~(size_t)255;
    return p;
  };
  float* s1src = (float*)alloc((size_t)NN * 8 * 4);
  float* s1dst = (float*)alloc((size_t)NN * 8 * 4);
  float* out1  = (float*)alloc((size_t)NN * 64 * 4);
  ushort* h1b  = (ushort*)alloc((size_t)NN * 64 * 2);
  __hip_bfloat162* h2b = (__hip_bfloat162*)alloc((size_t)NN * 128 * 2);
  int* row_off = (int*)alloc(((size_t)NN + 1) * 4);
  int* ssrc    = (int*)alloc((size_t)NE * 4);
  uint* pairs  = (uint*)alloc((size_t)NE * 4);
  ushort* Wt_hi = (ushort*)alloc((size_t)DF * 64 * 2);
  ushort* Wt_lo = (ushort*)alloc((size_t)DF * 64 * 2);
  int* bkt_cnt    = (int*)alloc(NBKT * 4);
  int* bkt_base   = (int*)alloc((NBKT + 1) * 4);
  int* bkt_cursor = (int*)alloc(NBKT * 4);

  dim3 b256(256);
  // W1 split/transpose (+ bkt_cnt zero), then layer-1 GEMM (MFMA, fused scores + bf16 h1)
  prep_w_kernel<<<dim3((DF * 64 + 255) / 256), b256, 0, stream>>>(W1, Wt_hi, Wt_lo, bkt_cnt);
  gemm1_mfma<<<dim3((NN + 127) / 128), b256, 0, stream>>>(x, Wt_hi, Wt_lo, a1s, a1d, h1b, s1src, s1dst);
  // CSR build via bucket sort
  bkt_hist_kernel<<<dim3(NBKT), b256, 0, stream>>>(edges, bkt_cnt);
  bkt_scan_kernel<<<dim3(1), dim3(NBKT), 0, stream>>>(bkt_cnt, bkt_base, bkt_cursor, row_off);
  bkt_reorder_kernel<<<dim3(NBKT), b256, 0, stream>>>(edges, bkt_cursor, pairs);
  bkt_build_kernel<<<dim3(NBKT), b256, 0, stream>>>(pairs, bkt_base, row_off, ssrc);
  // layer 1 aggregation (bf16 value gather)
  agg1_kernel<<<dim3(NN / 4), b256, 0, stream>>>(row_off, ssrc, s1src, s1dst, (const __hip_bfloat16*)h1b, out1, NN);
  // layer 2 GEMM with fused ELU + fused scores: h2b (bf16) = elu(out1) @ W2
  gemm2_fused<<<dim3((NN + 63) / 64, 2), b256, 0, stream>>>(out1, W2, h2b, a2s, a2d, s1src, s1dst, NN, 128, 64);
  // layer 2 aggregation over the 10k output indices only, writes d_out directly
  agg2_idx_kernel<<<dim3((NIDX * 64 + 255) / 256), b256, 0, stream>>>(row_off, ssrc, s1src, s1dst, h2b, indices, out, NIDX);
}